// Round 1
// baseline (3250.382 us; speedup 1.0000x reference)
//
#include <hip/hip_runtime.h>

// Problem: B=8192 samples, S=100 orbitals, H=512 hidden, 50 filled per spin.
// out[b] = det(up) * det(dn), dets of 50x50 gathered-row matrices.
// ws layout (floats): [mats 8192*2500][h 8192*512][rank 8192*100 (int)][detw 8192]
// total ~102 MB.

#define B_   8192
#define S_   100
#define H_   512
#define NF   50
#define W2N  5000
#define KC   32

// ---------------- K1: filled scan + h = relu(sum_{filled} W1 rows + b1) -------------
__global__ void k_hidden(const float* __restrict__ cfg, const float* __restrict__ W1,
                         const float* __restrict__ b1, float* __restrict__ h,
                         int* __restrict__ rank) {
  __shared__ int sFilled[NF];
  __shared__ int sRank[S_];
  int b = blockIdx.x;
  int t = threadIdx.x;
  if (t == 0) {
    int n = 0;
    for (int s = 0; s < S_; ++s) {
      float c = cfg[(size_t)b * 200 + s];
      if (c > 0.5f) { if (n < NF) { sFilled[n] = s; sRank[s] = n; } ++n; }
      else sRank[s] = -1;
    }
  }
  __syncthreads();
  if (t < S_) rank[(size_t)b * S_ + t] = sRank[t];
  float a0 = b1[t], a1 = b1[t + 256];
  #pragma unroll 5
  for (int i = 0; i < NF; ++i) {
    const float* w = W1 + (size_t)sFilled[i] * H_;
    a0 += w[t];
    a1 += w[t + 256];
  }
  h[(size_t)b * H_ + t]       = fmaxf(a0, 0.f);
  h[(size_t)b * H_ + t + 256] = fmaxf(a1, 0.f);
}

// ---------------- K2: gathered GEMM  mats[b][rank[b][s]][j] = h[b]·W2[:,s*50+j] + b2 ----
// grid (64, 25), block 256 = 4 waves. M-tile 128 rows (2 rows/lane), wave w owns s = 4*by+w.
__global__ void k_gemm(const float* __restrict__ h, const float* __restrict__ W2,
                       const float* __restrict__ b2, const int* __restrict__ rank,
                       float* __restrict__ mats) {
  __shared__ float sH[128][KC + 1];          // stride 33 -> conflict-free column reads
  __shared__ float sW[KC * 208];             // 4 s-slabs of 52 floats (16B aligned) per k-row
  int t = threadIdx.x;
  int wave = t >> 6, lane = t & 63;
  int m0 = blockIdx.x * 128;
  int s  = blockIdx.y * 4 + wave;
  float acc0[NF], acc1[NF];
  #pragma unroll
  for (int j = 0; j < NF; ++j) { acc0[j] = 0.f; acc1[j] = 0.f; }

  for (int k0 = 0; k0 < H_; k0 += KC) {
    __syncthreads();
    // stage H tile: 128 rows x 32 k (coalesced)
    #pragma unroll
    for (int i = 0; i < 128 * KC; i += 256) {
      int idx = i + t;
      int r = idx >> 5, c = idx & 31;
      sH[r][c] = h[(size_t)(m0 + r) * H_ + (k0 + c)];
    }
    // stage W2 slab: 32 k-rows x 200 cols (4 s-blocks), padded to 52/slab
    const float* wsrc = W2 + (size_t)k0 * W2N + blockIdx.y * 200;
    #pragma unroll
    for (int i = 0; i < KC * 200; i += 256) {
      int idx = i + t;
      int r = idx / 200, c = idx - r * 200;
      int sl = c / 50, j = c - sl * 50;
      sW[r * 208 + sl * 52 + j] = wsrc[(size_t)r * W2N + c];
    }
    __syncthreads();
    #pragma unroll 2
    for (int k = 0; k < KC; ++k) {
      float a0 = sH[lane][k];
      float a1 = sH[lane + 64][k];
      const float* wr = &sW[k * 208 + wave * 52];   // 16B-aligned, wave-uniform (broadcast)
      #pragma unroll
      for (int j = 0; j < NF; ++j) {
        float w = wr[j];
        acc0[j] = fmaf(a0, w, acc0[j]);
        acc1[j] = fmaf(a1, w, acc1[j]);
      }
    }
  }
  int b0 = m0 + lane, b1v = m0 + lane + 64;
  int p0 = rank[(size_t)b0  * S_ + s];
  int p1 = rank[(size_t)b1v * S_ + s];
  if (p0 >= 0) {
    float* dst = mats + (size_t)b0 * 2500 + p0 * NF;
    #pragma unroll
    for (int j = 0; j < NF; ++j) dst[j] = acc0[j] + b2[s * NF + j];
  }
  if (p1 >= 0) {
    float* dst = mats + (size_t)b1v * 2500 + p1 * NF;
    #pragma unroll
    for (int j = 0; j < NF; ++j) dst[j] = acc1[j] + b2[s * NF + j];
  }
}

// ---------------- K3: 50x50 LU det with partial pivoting, 1 wave per matrix -----------
// Rows register-resident (13 x float4), p-loop fully unrolled so all reg indices static.
__global__ void k_det(const float* __restrict__ mats, float* __restrict__ detw,
                      float* __restrict__ out, int spin) {
  __shared__ float sA[4][NF * 52];
  int t = threadIdx.x;
  int wave = t >> 6, lane = t & 63;
  int mb = blockIdx.x * 4 + wave;
  const float* src = mats + (size_t)mb * 2500;
  float* sa = sA[wave];
  for (int i = lane; i < 2500; i += 64) {      // coalesced load, LDS distribute
    int r = i / 50, c = i - r * 50;
    sa[r * 52 + c] = src[i];
  }
  if (lane < NF) { sa[lane * 52 + 50] = 0.f; sa[lane * 52 + 51] = 0.f; }
  __syncthreads();

  float4 row[13];
  if (lane < NF) {
    const float4* rp = (const float4*)(sa + lane * 52);
    #pragma unroll
    for (int q = 0; q < 13; ++q) row[q] = rp[q];
  } else {
    #pragma unroll
    for (int q = 0; q < 13; ++q) row[q] = make_float4(0.f, 0.f, 0.f, 0.f);
  }

  double detd = 1.0;
  int parity = 0;
  int virt = lane;                 // virtual permutation slot content (phys row at slot 'lane')
  bool active = (lane < NF);
  #pragma unroll
  for (int p = 0; p < NF; ++p) {
    const int q_ = p >> 2, e_ = p & 3;
    float4 rq = row[q_];
    float cp = (e_ == 0) ? rq.x : (e_ == 1) ? rq.y : (e_ == 2) ? rq.z : rq.w;
    // packed (|value|, lane) argmax over wave
    unsigned bits = __float_as_uint(fabsf(cp)) & 0xFFFFFFC0u;
    unsigned key = active ? (bits | (unsigned)lane) : 0u;
    #pragma unroll
    for (int mm = 32; mm >= 1; mm >>= 1) {
      unsigned o = (unsigned)__shfl_xor((int)key, mm);
      key = key > o ? key : o;
    }
    int pr = (int)(key & 63u);
    float v = __shfl(cp, pr);
    if (key < 64u) v = 0.f;        // all remaining pivots ~0 -> singular
    detd *= (double)v;
    // permutation parity via virtual swap
    int vp = __shfl(virt, p);
    unsigned long long bal = __ballot(virt == pr);
    int l = __ffsll((long long)bal) - 1;
    parity ^= (l != p) ? 1 : 0;
    virt = (lane == p) ? pr : ((lane == l) ? vp : virt);
    // eliminate
    float invv = (v != 0.f) ? (1.0f / v) : 0.f;
    float m = (active && lane != pr) ? (cp * invv) : 0.f;
    active = active && (lane != pr);
    #pragma unroll
    for (int q = (p + 1) >> 2; q < 13; ++q) {
      float4 pq;
      pq.x = __shfl(row[q].x, pr);
      pq.y = __shfl(row[q].y, pr);
      pq.z = __shfl(row[q].z, pr);
      pq.w = __shfl(row[q].w, pr);
      row[q].x = fmaf(-m, pq.x, row[q].x);
      row[q].y = fmaf(-m, pq.y, row[q].y);
      row[q].z = fmaf(-m, pq.z, row[q].z);
      row[q].w = fmaf(-m, pq.w, row[q].w);
    }
  }
  float det = (float)detd;
  if (parity) det = -det;
  if (lane == 0) {
    if (spin == 0) detw[mb] = det;
    else           out[mb]  = detw[mb] * det;
  }
}

extern "C" void kernel_launch(void* const* d_in, const int* in_sizes, int n_in,
                              void* d_out, int out_size, void* d_ws, size_t ws_size,
                              hipStream_t stream) {
  const float* cfg = (const float*)d_in[0];
  float* ws   = (float*)d_ws;
  float* mats = ws;                                   // 8192*2500
  float* h    = ws + (size_t)B_ * 2500;               // 8192*512
  int*   rank = (int*)(h + (size_t)B_ * H_);          // 8192*100
  float* detw = (float*)(rank + (size_t)B_ * S_);     // 8192
  float* out  = (float*)d_out;

  for (int spin = 0; spin < 2; ++spin) {
    const float* W1 = (const float*)d_in[1 + spin * 4];
    const float* b1 = (const float*)d_in[2 + spin * 4];
    const float* W2 = (const float*)d_in[3 + spin * 4];
    const float* b2 = (const float*)d_in[4 + spin * 4];
    k_hidden<<<B_, 256, 0, stream>>>(cfg + spin * S_, W1, b1, h, rank);
    k_gemm<<<dim3(64, 25), 256, 0, stream>>>(h, W2, b2, rank, mats);
    k_det<<<B_ / 4, 256, 0, stream>>>(mats, detw, out, spin);
  }
}

// Round 2
// 2047.774 us; speedup vs baseline: 1.5873x; 1.5873x over previous
//
#include <hip/hip_runtime.h>

// B=8192, S=100, H=512, NF=50 filled per spin.
// Pipeline per spin: k_zero -> k_hidden (h + per-s compacted sample lists)
// -> k_pad -> k_gemm (gathered rows x 50 cols, fp32 outer-product tile)
// -> k_det (50x50 LU, wave-per-matrix).
// ws floats: [mats 8192*2500][h 8192*512][list 100*8192 int][cnt 128][detw 8192]

#define B_   8192
#define S_   100
#define H_   512
#define NF   50
#define W2N  5000
#define NT   512      // rows per gemm block
#define KC   16       // k-chunk
#define LCAP 8192

__global__ void k_zero(int* __restrict__ cnt) {
  if (threadIdx.x < S_) cnt[threadIdx.x] = 0;
}

// ---- K1: h = relu(sum_{filled} W1 rows + b1); append (b<<6|rank) to list[s] ----
__global__ void k_hidden(const float* __restrict__ cfg, const float* __restrict__ W1,
                         const float* __restrict__ b1, float* __restrict__ h,
                         int* __restrict__ list, int* __restrict__ cnt) {
  __shared__ int sFilled[NF];
  __shared__ int sRank[S_];
  int b = blockIdx.x;
  int t = threadIdx.x;
  if (t == 0) {
    int n = 0;
    for (int s = 0; s < S_; ++s) {
      float c = cfg[(size_t)b * 200 + s];
      if (c > 0.5f) { if (n < NF) { sFilled[n] = s; sRank[s] = n; } ++n; }
      else sRank[s] = -1;
    }
  }
  __syncthreads();
  if (t < S_) {
    int p = sRank[t];
    if (p >= 0) {
      int pos = atomicAdd(&cnt[t], 1);
      list[t * LCAP + pos] = (b << 6) | p;
    }
  }
  float a0 = b1[t], a1 = b1[t + 256];
  #pragma unroll 5
  for (int i = 0; i < NF; ++i) {
    const float* w = W1 + (size_t)sFilled[i] * H_;
    a0 += w[t];
    a1 += w[t + 256];
  }
  h[(size_t)b * H_ + t]       = fmaxf(a0, 0.f);
  h[(size_t)b * H_ + t + 256] = fmaxf(a1, 0.f);
}

// ---- K1b: pad each list to a multiple of NT with -1 ----
__global__ void k_pad(int* __restrict__ list, const int* __restrict__ cnt) {
  int s = blockIdx.x;
  int c = cnt[s];
  int end = (c + NT - 1) & ~(NT - 1);
  for (int i = c + threadIdx.x; i < end; i += 256) list[s * LCAP + i] = -1;
}

// ---- K2: gathered GEMM. grid (16, 100), block 256 = 4 waves.
// Block: 512 gathered rows x 50 cols (one s). Wave: 128 rows. Lane (rg,cg)=(l>>2,l&3):
// 8 rows (stride 16) x 13 cols -> 104 accumulators.
__global__ void __launch_bounds__(256, 3)
k_gemm(const float* __restrict__ h, const float* __restrict__ W2,
       const float* __restrict__ b2, const int* __restrict__ list,
       const int* __restrict__ cnt, float* __restrict__ mats) {
  __shared__ float sH[NT * 20];       // row-major, stride 20 (16B-aligned rows, 2-way max)
  __shared__ float sW[KC * 64];       // per k: 4 col-groups x 16 (13 used + 3 zero pad)
  __shared__ int   sRows[NT];
  int t = threadIdx.x;
  int s = blockIdx.y;
  int c = cnt[s];
  int padded = (c + NT - 1) & ~(NT - 1);
  if ((int)blockIdx.x * NT >= padded) return;
  int row0 = blockIdx.x * NT;

  sRows[t]       = list[s * LCAP + row0 + t];
  sRows[t + 256] = list[s * LCAP + row0 + t + 256];
  // zero sW once: pad lanes stay 0 forever
  #pragma unroll
  for (int i = 0; i < KC * 64; i += 256) sW[i + t] = 0.f;

  int wave = t >> 6, lane = t & 63;
  int rg = lane >> 2, cg = lane & 3;
  int wbase = wave * 128;

  float acc[8][13];
  #pragma unroll
  for (int i = 0; i < 8; ++i)
    #pragma unroll
    for (int j = 0; j < 13; ++j) acc[i][j] = 0.f;

  for (int k0 = 0; k0 < H_; k0 += KC) {
    __syncthreads();
    // stage 512 rows x 16 k (float4 per thread x8)
    #pragma unroll
    for (int i = 0; i < 8; ++i) {
      int idx = i * 256 + t;
      int r = idx >> 2, c4 = idx & 3;
      int v = sRows[r];
      int g = (v < 0) ? 0 : (v >> 6);
      float4 hv = *(const float4*)(h + (size_t)g * H_ + k0 + c4 * 4);
      *(float4*)(sH + r * 20 + c4 * 4) = hv;
    }
    // stage W2 slab: 16 k x 50 cols -> group-padded 16x64
    #pragma unroll
    for (int i = 0; i < 4; ++i) {
      int idx = i * 256 + t;
      if (idx < KC * 50) {
        int r = idx / 50, j = idx - r * 50;
        int g4 = j / 13, jj = j - g4 * 13;
        sW[r * 64 + g4 * 16 + jj] = W2[(size_t)(k0 + r) * W2N + s * NF + j];
      }
    }
    __syncthreads();
    #pragma unroll 2
    for (int k = 0; k < KC; ++k) {
      float bb[16];
      *(float4*)&bb[0]  = *(const float4*)(sW + k * 64 + cg * 16);
      *(float4*)&bb[4]  = *(const float4*)(sW + k * 64 + cg * 16 + 4);
      *(float4*)&bb[8]  = *(const float4*)(sW + k * 64 + cg * 16 + 8);
      *(float4*)&bb[12] = *(const float4*)(sW + k * 64 + cg * 16 + 12);
      float av[8];
      #pragma unroll
      for (int i = 0; i < 8; ++i) av[i] = sH[(wbase + rg + 16 * i) * 20 + k];
      #pragma unroll
      for (int i = 0; i < 8; ++i)
        #pragma unroll
        for (int j = 0; j < 13; ++j)
          acc[i][j] = fmaf(av[i], bb[j], acc[i][j]);
    }
  }
  // epilogue: bias + gathered write of 13-col strip
  float bcol[13];
  #pragma unroll
  for (int j = 0; j < 13; ++j) {
    int col = cg * 13 + j;
    bcol[j] = (col < NF) ? b2[s * NF + col] : 0.f;
  }
  #pragma unroll
  for (int i = 0; i < 8; ++i) {
    int r = wbase + rg + 16 * i;
    int v = sRows[r];
    if (v >= 0) {
      int g = v >> 6, p = v & 63;
      float* dst = mats + (size_t)g * 2500 + p * NF + cg * 13;
      #pragma unroll
      for (int j = 0; j < 13; ++j)
        if (cg * 13 + j < NF) dst[j] = acc[i][j] + bcol[j];
    }
  }
}

// ---- K3: 50x50 LU det with partial pivoting, 1 wave per matrix ----
__global__ void k_det(const float* __restrict__ mats, float* __restrict__ detw,
                      float* __restrict__ out, int spin) {
  __shared__ float sA[4][NF * 52];
  int t = threadIdx.x;
  int wave = t >> 6, lane = t & 63;
  int mb = blockIdx.x * 4 + wave;
  const float* src = mats + (size_t)mb * 2500;
  float* sa = sA[wave];
  for (int i = lane; i < 2500; i += 64) {
    int r = i / 50, c = i - r * 50;
    sa[r * 52 + c] = src[i];
  }
  if (lane < NF) { sa[lane * 52 + 50] = 0.f; sa[lane * 52 + 51] = 0.f; }
  __syncthreads();

  float4 row[13];
  if (lane < NF) {
    const float4* rp = (const float4*)(sa + lane * 52);
    #pragma unroll
    for (int q = 0; q < 13; ++q) row[q] = rp[q];
  } else {
    #pragma unroll
    for (int q = 0; q < 13; ++q) row[q] = make_float4(0.f, 0.f, 0.f, 0.f);
  }

  double detd = 1.0;
  int parity = 0;
  int virt = lane;
  bool active = (lane < NF);
  #pragma unroll
  for (int p = 0; p < NF; ++p) {
    const int q_ = p >> 2, e_ = p & 3;
    float4 rq = row[q_];
    float cp = (e_ == 0) ? rq.x : (e_ == 1) ? rq.y : (e_ == 2) ? rq.z : rq.w;
    unsigned bits = __float_as_uint(fabsf(cp)) & 0xFFFFFFC0u;
    unsigned key = active ? (bits | (unsigned)lane) : 0u;
    #pragma unroll
    for (int mm = 32; mm >= 1; mm >>= 1) {
      unsigned o = (unsigned)__shfl_xor((int)key, mm);
      key = key > o ? key : o;
    }
    int pr = (int)(key & 63u);
    float v = __shfl(cp, pr);
    if (key < 64u) v = 0.f;
    detd *= (double)v;
    int vp = __shfl(virt, p);
    unsigned long long bal = __ballot(virt == pr);
    int l = __ffsll((long long)bal) - 1;
    parity ^= (l != p) ? 1 : 0;
    virt = (lane == p) ? pr : ((lane == l) ? vp : virt);
    float invv = (v != 0.f) ? (1.0f / v) : 0.f;
    float m = (active && lane != pr) ? (cp * invv) : 0.f;
    active = active && (lane != pr);
    #pragma unroll
    for (int q = (p + 1) >> 2; q < 13; ++q) {
      float4 pq;
      pq.x = __shfl(row[q].x, pr);
      pq.y = __shfl(row[q].y, pr);
      pq.z = __shfl(row[q].z, pr);
      pq.w = __shfl(row[q].w, pr);
      row[q].x = fmaf(-m, pq.x, row[q].x);
      row[q].y = fmaf(-m, pq.y, row[q].y);
      row[q].z = fmaf(-m, pq.z, row[q].z);
      row[q].w = fmaf(-m, pq.w, row[q].w);
    }
  }
  float det = (float)detd;
  if (parity) det = -det;
  if (lane == 0) {
    if (spin == 0) detw[mb] = det;
    else           out[mb]  = detw[mb] * det;
  }
}

extern "C" void kernel_launch(void* const* d_in, const int* in_sizes, int n_in,
                              void* d_out, int out_size, void* d_ws, size_t ws_size,
                              hipStream_t stream) {
  const float* cfg = (const float*)d_in[0];
  float* ws   = (float*)d_ws;
  float* mats = ws;                                   // 8192*2500
  float* h    = ws + (size_t)B_ * 2500;               // 8192*512
  int*   list = (int*)(h + (size_t)B_ * H_);          // 100*8192
  int*   cnt  = list + (size_t)S_ * LCAP;             // 128
  float* detw = (float*)(cnt + 128);                  // 8192
  float* out  = (float*)d_out;

  for (int spin = 0; spin < 2; ++spin) {
    const float* W1 = (const float*)d_in[1 + spin * 4];
    const float* b1 = (const float*)d_in[2 + spin * 4];
    const float* W2 = (const float*)d_in[3 + spin * 4];
    const float* b2 = (const float*)d_in[4 + spin * 4];
    k_zero  <<<1, 128, 0, stream>>>(cnt);
    k_hidden<<<B_, 256, 0, stream>>>(cfg + spin * S_, W1, b1, h, list, cnt);
    k_pad   <<<S_, 256, 0, stream>>>(list, cnt);
    k_gemm  <<<dim3(16, S_), 256, 0, stream>>>(h, W2, b2, list, cnt, mats);
    k_det   <<<B_ / 4, 256, 0, stream>>>(mats, detw, out, spin);
  }
}

// Round 3
// 1527.601 us; speedup vs baseline: 2.1278x; 1.3405x over previous
//
#include <hip/hip_runtime.h>

// B=8192, S=100, H=512, NF=50 filled per spin.
// Split-fp16 MFMA pipeline per spin:
//   k_zero -> k_hidden (h split to fp16 hi/lo x256, per-s lists)
//   k_splitw2 (W2 -> transposed [s][col][k] fp16 hi/lo x4096)
//   k_pad -> k_gemm (gathered 512-row x 64-col tiles, 4 mfma products)
//   k_det (50x50 LU, wave-per-matrix)
// ws bytes: mats 81.9M | hh 8.4M | hl 8.4M | w2h 5.1M | w2l 5.1M | list 3.3M | cnt | detw

#define B_   8192
#define S_   100
#define H_   512
#define NF   50
#define W2N  5000
#define NT   512
#define LCAP 8192

typedef _Float16 half8 __attribute__((ext_vector_type(8)));
typedef float f32x16 __attribute__((ext_vector_type(16)));
typedef unsigned short ushort_t;

__device__ __forceinline__ ushort_t f2h(float x) {
  _Float16 h = (_Float16)x;
  return __builtin_bit_cast(ushort_t, h);
}
__device__ __forceinline__ float h2f(ushort_t u) {
  return (float)__builtin_bit_cast(_Float16, u);
}

#define SCALE_H 256.0f
#define SCALE_W 4096.0f

__global__ void k_zero(int* __restrict__ cnt) {
  if (threadIdx.x < S_) cnt[threadIdx.x] = 0;
}

// ---- K1: h rows (fp16 hi/lo, x256) + per-s compacted lists ----
__global__ void k_hidden(const float* __restrict__ cfg, const float* __restrict__ W1,
                         const float* __restrict__ b1, ushort_t* __restrict__ hh,
                         ushort_t* __restrict__ hl,
                         int* __restrict__ list, int* __restrict__ cnt) {
  __shared__ int sFilled[NF];
  __shared__ int sRank[S_];
  int b = blockIdx.x;
  int t = threadIdx.x;
  if (t == 0) {
    int n = 0;
    for (int s = 0; s < S_; ++s) {
      float c = cfg[(size_t)b * 200 + s];
      if (c > 0.5f) { if (n < NF) { sFilled[n] = s; sRank[s] = n; } ++n; }
      else sRank[s] = -1;
    }
  }
  __syncthreads();
  if (t < S_) {
    int p = sRank[t];
    if (p >= 0) {
      int pos = atomicAdd(&cnt[t], 1);
      list[t * LCAP + pos] = (b << 6) | p;
    }
  }
  float a0 = b1[t], a1 = b1[t + 256];
  #pragma unroll 5
  for (int i = 0; i < NF; ++i) {
    const float* w = W1 + (size_t)sFilled[i] * H_;
    a0 += w[t];
    a1 += w[t + 256];
  }
  a0 = fmaxf(a0, 0.f) * SCALE_H;
  a1 = fmaxf(a1, 0.f) * SCALE_H;
  ushort_t h0 = f2h(a0), h1 = f2h(a1);
  hh[(size_t)b * H_ + t]       = h0;
  hh[(size_t)b * H_ + t + 256] = h1;
  hl[(size_t)b * H_ + t]       = f2h(a0 - h2f(h0));
  hl[(size_t)b * H_ + t + 256] = f2h(a1 - h2f(h1));
}

// ---- K1b: W2 -> W2T[s][col][k] fp16 hi/lo, scaled x4096 ----
__global__ void k_splitw2(const float* __restrict__ W2, ushort_t* __restrict__ w2h,
                          ushort_t* __restrict__ w2l) {
  __shared__ float sT[64][52];
  int s = blockIdx.x;
  int k0 = blockIdx.y * 64;
  int t = threadIdx.x;
  for (int i = t; i < 64 * 50; i += 256) {
    int r = i / 50, c = i - r * 50;
    sT[r][c] = W2[(size_t)(k0 + r) * W2N + s * NF + c] * SCALE_W;
  }
  __syncthreads();
  if (t < 200) {
    int c = t >> 2, kq = t & 3;
    ushort_t hb[16], lb[16];
    #pragma unroll
    for (int j = 0; j < 16; ++j) {
      float v = sT[kq * 16 + j][c];
      ushort_t hv = f2h(v);
      hb[j] = hv;
      lb[j] = f2h(v - h2f(hv));
    }
    ushort_t* dh = w2h + ((size_t)s * NF + c) * H_ + k0 + kq * 16;
    ushort_t* dl = w2l + ((size_t)s * NF + c) * H_ + k0 + kq * 16;
    #pragma unroll
    for (int j = 0; j < 16; ++j) { dh[j] = hb[j]; dl[j] = lb[j]; }
  }
}

// ---- K1c: pad lists to multiple of NT ----
__global__ void k_pad(int* __restrict__ list, const int* __restrict__ cnt) {
  int s = blockIdx.x;
  int c = cnt[s];
  int end = (c + NT - 1) & ~(NT - 1);
  for (int i = c + threadIdx.x; i < end; i += 256) list[s * LCAP + i] = -1;
}

// ---- K2: gathered split-fp16 MFMA GEMM ----
// grid (16, 100), block 256 = 4 waves. Block: 512 gathered rows x 64 cols (one s).
// Wave: 128 rows x 64 cols = 4x2 tiles of 32x32. BK=32 (2 mfma k-steps).
__global__ void __launch_bounds__(256, 2)
k_gemm(const ushort_t* __restrict__ hh, const ushort_t* __restrict__ hl,
       const ushort_t* __restrict__ w2h, const ushort_t* __restrict__ w2l,
       const float* __restrict__ b2, const int* __restrict__ list,
       const int* __restrict__ cnt, float* __restrict__ mats) {
  __shared__ __align__(16) ushort_t sAh[4][NT][8];   // 32KB, k-octet major
  __shared__ __align__(16) ushort_t sAl[4][NT][8];   // 32KB
  __shared__ __align__(16) ushort_t sBh[4][64][8];   // 4KB
  __shared__ __align__(16) ushort_t sBl[4][64][8];   // 4KB
  __shared__ int sRows[NT];
  int t = threadIdx.x;
  int s = blockIdx.y;
  int c = cnt[s];
  int padded = (c + NT - 1) & ~(NT - 1);
  if ((int)blockIdx.x * NT >= padded) return;
  int row0 = blockIdx.x * NT;
  sRows[t]       = list[s * LCAP + row0 + t];
  sRows[t + 256] = list[s * LCAP + row0 + t + 256];

  // zero pad cols of B once (never overwritten)
  int bc = t & 63, bq = t >> 6;
  if (bc >= NF) {
    *(uint4*)&sBh[bq][bc][0] = make_uint4(0, 0, 0, 0);
    *(uint4*)&sBl[bq][bc][0] = make_uint4(0, 0, 0, 0);
  }
  __syncthreads();

  int v0 = sRows[t], v1 = sRows[t + 256];
  const ushort_t* a0h = hh + (size_t)((v0 < 0) ? 0 : (v0 >> 6)) * H_;
  const ushort_t* a0l = hl + (size_t)((v0 < 0) ? 0 : (v0 >> 6)) * H_;
  const ushort_t* a1h = hh + (size_t)((v1 < 0) ? 0 : (v1 >> 6)) * H_;
  const ushort_t* a1l = hl + (size_t)((v1 < 0) ? 0 : (v1 >> 6)) * H_;
  const ushort_t* wbh = w2h + ((size_t)s * NF + bc) * H_ + bq * 8;
  const ushort_t* wbl = w2l + ((size_t)s * NF + bc) * H_ + bq * 8;
  bool bc_ok = bc < NF;

  int wave = t >> 6, lane = t & 63;
  int l5 = lane >> 5, l31 = lane & 31;
  int wbase = wave * 128;

  f32x16 acc[4][2];
  #pragma unroll
  for (int rt = 0; rt < 4; ++rt)
    #pragma unroll
    for (int ct = 0; ct < 2; ++ct) acc[rt][ct] = (f32x16)(0.f);

  for (int k0 = 0; k0 < H_; k0 += 32) {
    __syncthreads();
    #pragma unroll
    for (int q = 0; q < 4; ++q) {
      *(uint4*)&sAh[q][t][0]       = *(const uint4*)(a0h + k0 + q * 8);
      *(uint4*)&sAl[q][t][0]       = *(const uint4*)(a0l + k0 + q * 8);
      *(uint4*)&sAh[q][t + 256][0] = *(const uint4*)(a1h + k0 + q * 8);
      *(uint4*)&sAl[q][t + 256][0] = *(const uint4*)(a1l + k0 + q * 8);
    }
    if (bc_ok) {
      *(uint4*)&sBh[bq][bc][0] = *(const uint4*)(wbh + k0);
      *(uint4*)&sBl[bq][bc][0] = *(const uint4*)(wbl + k0);
    }
    __syncthreads();
    #pragma unroll
    for (int step = 0; step < 2; ++step) {
      half8 bhf[2], blf[2], ahf[4], alf[4];
      #pragma unroll
      for (int ct = 0; ct < 2; ++ct) {
        bhf[ct] = *(const half8*)&sBh[step * 2 + l5][ct * 32 + l31][0];
        blf[ct] = *(const half8*)&sBl[step * 2 + l5][ct * 32 + l31][0];
      }
      #pragma unroll
      for (int rt = 0; rt < 4; ++rt) {
        ahf[rt] = *(const half8*)&sAh[step * 2 + l5][wbase + rt * 32 + l31][0];
        alf[rt] = *(const half8*)&sAl[step * 2 + l5][wbase + rt * 32 + l31][0];
      }
      #pragma unroll
      for (int rt = 0; rt < 4; ++rt)
        #pragma unroll
        for (int ct = 0; ct < 2; ++ct) {
          acc[rt][ct] = __builtin_amdgcn_mfma_f32_32x32x16_f16(ahf[rt], bhf[ct], acc[rt][ct], 0, 0, 0);
          acc[rt][ct] = __builtin_amdgcn_mfma_f32_32x32x16_f16(ahf[rt], blf[ct], acc[rt][ct], 0, 0, 0);
          acc[rt][ct] = __builtin_amdgcn_mfma_f32_32x32x16_f16(alf[rt], bhf[ct], acc[rt][ct], 0, 0, 0);
          acc[rt][ct] = __builtin_amdgcn_mfma_f32_32x32x16_f16(alf[rt], blf[ct], acc[rt][ct], 0, 0, 0);
        }
    }
  }

  const float invs = 1.0f / (SCALE_H * SCALE_W);
  #pragma unroll
  for (int rt = 0; rt < 4; ++rt) {
    #pragma unroll
    for (int ct = 0; ct < 2; ++ct) {
      int col = ct * 32 + l31;
      float bias = (col < NF) ? b2[s * NF + col] : 0.f;
      #pragma unroll
      for (int reg = 0; reg < 16; ++reg) {
        int rloc = (reg & 3) + 8 * (reg >> 2) + 4 * l5;
        int r = wbase + rt * 32 + rloc;
        int v = sRows[r];
        if (v >= 0 && col < NF) {
          int g = v >> 6, p = v & 63;
          mats[(size_t)g * 2500 + p * NF + col] = acc[rt][ct][reg] * invs + bias;
        }
      }
    }
  }
}

// ---- K3: 50x50 LU det with partial pivoting, 1 wave per matrix ----
__global__ void k_det(const float* __restrict__ mats, float* __restrict__ detw,
                      float* __restrict__ out, int spin) {
  __shared__ float sA[4][NF * 52];
  int t = threadIdx.x;
  int wave = t >> 6, lane = t & 63;
  int mb = blockIdx.x * 4 + wave;
  const float* src = mats + (size_t)mb * 2500;
  float* sa = sA[wave];
  for (int i = lane; i < 2500; i += 64) {
    int r = i / 50, c = i - r * 50;
    sa[r * 52 + c] = src[i];
  }
  if (lane < NF) { sa[lane * 52 + 50] = 0.f; sa[lane * 52 + 51] = 0.f; }
  __syncthreads();

  float4 row[13];
  if (lane < NF) {
    const float4* rp = (const float4*)(sa + lane * 52);
    #pragma unroll
    for (int q = 0; q < 13; ++q) row[q] = rp[q];
  } else {
    #pragma unroll
    for (int q = 0; q < 13; ++q) row[q] = make_float4(0.f, 0.f, 0.f, 0.f);
  }

  double detd = 1.0;
  int parity = 0;
  int virt = lane;
  bool active = (lane < NF);
  #pragma unroll
  for (int p = 0; p < NF; ++p) {
    const int q_ = p >> 2, e_ = p & 3;
    float4 rq = row[q_];
    float cp = (e_ == 0) ? rq.x : (e_ == 1) ? rq.y : (e_ == 2) ? rq.z : rq.w;
    unsigned bits = __float_as_uint(fabsf(cp)) & 0xFFFFFFC0u;
    unsigned key = active ? (bits | (unsigned)lane) : 0u;
    #pragma unroll
    for (int mm = 32; mm >= 1; mm >>= 1) {
      unsigned o = (unsigned)__shfl_xor((int)key, mm);
      key = key > o ? key : o;
    }
    int pr = (int)(key & 63u);
    float v = __shfl(cp, pr);
    if (key < 64u) v = 0.f;
    detd *= (double)v;
    int vp = __shfl(virt, p);
    unsigned long long bal = __ballot(virt == pr);
    int l = __ffsll((long long)bal) - 1;
    parity ^= (l != p) ? 1 : 0;
    virt = (lane == p) ? pr : ((lane == l) ? vp : virt);
    float invv = (v != 0.f) ? (1.0f / v) : 0.f;
    float m = (active && lane != pr) ? (cp * invv) : 0.f;
    active = active && (lane != pr);
    #pragma unroll
    for (int q = (p + 1) >> 2; q < 13; ++q) {
      float4 pq;
      pq.x = __shfl(row[q].x, pr);
      pq.y = __shfl(row[q].y, pr);
      pq.z = __shfl(row[q].z, pr);
      pq.w = __shfl(row[q].w, pr);
      row[q].x = fmaf(-m, pq.x, row[q].x);
      row[q].y = fmaf(-m, pq.y, row[q].y);
      row[q].z = fmaf(-m, pq.z, row[q].z);
      row[q].w = fmaf(-m, pq.w, row[q].w);
    }
  }
  float det = (float)detd;
  if (parity) det = -det;
  if (lane == 0) {
    if (spin == 0) detw[mb] = det;
    else           out[mb]  = detw[mb] * det;
  }
}

extern "C" void kernel_launch(void* const* d_in, const int* in_sizes, int n_in,
                              void* d_out, int out_size, void* d_ws, size_t ws_size,
                              hipStream_t stream) {
  const float* cfg = (const float*)d_in[0];
  char* ws = (char*)d_ws;
  float*    mats = (float*)ws;                                  ws += (size_t)B_ * 2500 * 4;
  ushort_t* hh   = (ushort_t*)ws;                               ws += (size_t)B_ * H_ * 2;
  ushort_t* hl   = (ushort_t*)ws;                               ws += (size_t)B_ * H_ * 2;
  ushort_t* w2h  = (ushort_t*)ws;                               ws += (size_t)S_ * NF * H_ * 2;
  ushort_t* w2l  = (ushort_t*)ws;                               ws += (size_t)S_ * NF * H_ * 2;
  int*      list = (int*)ws;                                    ws += (size_t)S_ * LCAP * 4;
  int*      cnt  = (int*)ws;                                    ws += 512;
  float*    detw = (float*)ws;
  float*    out  = (float*)d_out;

  for (int spin = 0; spin < 2; ++spin) {
    const float* W1 = (const float*)d_in[1 + spin * 4];
    const float* b1 = (const float*)d_in[2 + spin * 4];
    const float* W2 = (const float*)d_in[3 + spin * 4];
    const float* b2 = (const float*)d_in[4 + spin * 4];
    k_zero   <<<1, 128, 0, stream>>>(cnt);
    k_hidden <<<B_, 256, 0, stream>>>(cfg + spin * S_, W1, b1, hh, hl, list, cnt);
    k_splitw2<<<dim3(S_, 8), 256, 0, stream>>>(W2, w2h, w2l);
    k_pad    <<<S_, 256, 0, stream>>>(list, cnt);
    k_gemm   <<<dim3(LCAP / NT, S_), 256, 0, stream>>>(hh, hl, w2h, w2l, b2, list, cnt, mats);
    k_det    <<<B_ / 4, 256, 0, stream>>>(mats, detw, out, spin);
  }
}

// Round 4
// 1300.731 us; speedup vs baseline: 2.4989x; 1.1744x over previous
//
#include <hip/hip_runtime.h>

// B=8192, S=100, H=512, NF=50 filled per spin.
// Per spin: k_splitw2 (W2 -> [s][64col][k] fp16 hi/lo, zero-pad cols; also zeros cnt)
//   -> k_hidden (ballot-rank scan, h split fp16 hi/lo, per-s lists)
//   -> k_pad -> k_gemm (gathered 256-row x 64-col tiles, global_load_lds staging,
//                        3-product split-fp16 MFMA) -> k_det (50x50 LU, wave/matrix).

#define B_   8192
#define S_   100
#define H_   512
#define NF   50
#define W2N  5000
#define NT   256
#define LCAP 8192
#define SCALE_H 256.0f
#define SCALE_W 4096.0f

typedef _Float16 half8 __attribute__((ext_vector_type(8)));
typedef float f32x16 __attribute__((ext_vector_type(16)));
typedef unsigned short u16;
typedef unsigned int u32;

__device__ __forceinline__ u16 f2h(float x) {
  _Float16 h = (_Float16)x;
  return __builtin_bit_cast(u16, h);
}
__device__ __forceinline__ float h2f(u16 u) {
  return (float)__builtin_bit_cast(_Float16, u);
}

// CK-style cast pattern for global_load_lds (direct global->LDS, 16B/lane).
__device__ __forceinline__ void gload_lds16(const void* g, void* l) {
  __builtin_amdgcn_global_load_lds(
      reinterpret_cast<const __attribute__((address_space(1))) u32*>(
          reinterpret_cast<uintptr_t>(g)),
      reinterpret_cast<__attribute__((address_space(3))) u32*>(
          reinterpret_cast<uintptr_t>(l)),
      16, 0, 0);
}

// ---- K0: W2 -> W2T[s][64 cols][512 k] fp16 hi/lo (x4096), cols 50..63 zero.
//          Block (0,0) also zeros cnt.
__global__ void k_splitw2(const float* __restrict__ W2, u16* __restrict__ w2h,
                          u16* __restrict__ w2l, int* __restrict__ cnt) {
  __shared__ float sT[64][65];
  int s = blockIdx.x, k0 = blockIdx.y * 64, t = threadIdx.x;
  if (blockIdx.x == 0 && blockIdx.y == 0 && t < 128) cnt[t] = 0;
  for (int i = t; i < 64 * 50; i += 256) {
    int r = i / 50, cc = i - r * 50;
    sT[r][cc] = W2[(size_t)(k0 + r) * W2N + s * NF + cc] * SCALE_W;
  }
  for (int i = t; i < 64 * 14; i += 256) {
    int r = i / 14, cc = 50 + (i - r * 14);
    sT[r][cc] = 0.f;
  }
  __syncthreads();
  int cc = t >> 2, rq = t & 3;
  __align__(16) u16 hb[16], lb[16];
  #pragma unroll
  for (int j = 0; j < 16; ++j) {
    float v = sT[rq * 16 + j][cc];
    u16 hv = f2h(v);
    hb[j] = hv;
    lb[j] = f2h(v - h2f(hv));
  }
  u16* dh = w2h + ((size_t)s * 64 + cc) * H_ + k0 + rq * 16;
  u16* dl = w2l + ((size_t)s * 64 + cc) * H_ + k0 + rq * 16;
  *(uint4*)dh = *(const uint4*)&hb[0];
  *(uint4*)(dh + 8) = *(const uint4*)&hb[8];
  *(uint4*)dl = *(const uint4*)&lb[0];
  *(uint4*)(dl + 8) = *(const uint4*)&lb[8];
}

// ---- K1: ballot-rank scan + h = relu(sum W1 rows + b1), fp16 hi/lo split ----
__global__ void k_hidden(const float* __restrict__ cfg, const float* __restrict__ W1,
                         const float* __restrict__ b1, u16* __restrict__ hh,
                         u16* __restrict__ hl, int* __restrict__ list,
                         int* __restrict__ cnt) {
  __shared__ int sFilled[NF];
  __shared__ unsigned long long sM0;
  int b = blockIdx.x, t = threadIdx.x;
  bool f = (t < S_) ? (cfg[(size_t)b * 200 + t] > 0.5f) : false;
  unsigned long long m = __ballot(f);
  if (t == 0) sM0 = m;
  __syncthreads();
  if (f) {
    int lane = t & 63;
    int below = __popcll(m & ((1ULL << lane) - 1ULL));
    int r = (t < 64) ? below : (__popcll(sM0) + below);
    sFilled[r] = t;
    int pos = atomicAdd(&cnt[t], 1);
    list[t * LCAP + pos] = (b << 6) | r;
  }
  __syncthreads();
  float a0 = b1[t], a1 = b1[t + 256];
  #pragma unroll 5
  for (int i = 0; i < NF; ++i) {
    const float* w = W1 + (size_t)sFilled[i] * H_;
    a0 += w[t];
    a1 += w[t + 256];
  }
  a0 = fmaxf(a0, 0.f) * SCALE_H;
  a1 = fmaxf(a1, 0.f) * SCALE_H;
  u16 h0 = f2h(a0), h1 = f2h(a1);
  hh[(size_t)b * H_ + t]       = h0;
  hh[(size_t)b * H_ + t + 256] = h1;
  hl[(size_t)b * H_ + t]       = f2h(a0 - h2f(h0));
  hl[(size_t)b * H_ + t + 256] = f2h(a1 - h2f(h1));
}

// ---- K1c: pad lists to multiple of NT ----
__global__ void k_pad(int* __restrict__ list, const int* __restrict__ cnt) {
  int s = blockIdx.x;
  int c = cnt[s];
  int end = (c + NT - 1) & ~(NT - 1);
  for (int i = c + threadIdx.x; i < end; i += 256) list[s * LCAP + i] = -1;
}

// ---- K2: gathered 3-product split-fp16 MFMA GEMM, global_load_lds staging ----
// grid (32, 100), block 256 = 4 waves. Block: 256 gathered rows x 64 cols (one s).
// Wave tile 64x64 (2x2 of 32x32). BK=32 (2 mfma k-steps). Wave w stages k-octet w.
__global__ void __launch_bounds__(256, 3)
k_gemm(const u16* __restrict__ hh, const u16* __restrict__ hl,
       const u16* __restrict__ w2h, const u16* __restrict__ w2l,
       const float* __restrict__ b2, const int* __restrict__ list,
       const int* __restrict__ cnt, float* __restrict__ mats) {
  __shared__ __align__(16) u16 sAh[4][NT][8];   // 16 KB
  __shared__ __align__(16) u16 sAl[4][NT][8];   // 16 KB
  __shared__ __align__(16) u16 sBh[4][64][8];   // 4 KB
  __shared__ __align__(16) u16 sBl[4][64][8];   // 4 KB
  __shared__ int sRows[NT];                     // 1 KB  -> 41 KB total, 3 blocks/CU
  int t = threadIdx.x;
  int s = blockIdx.y;
  int c = cnt[s];
  int padded = (c + NT - 1) & ~(NT - 1);
  if ((int)blockIdx.x * NT >= padded) return;
  int row0 = blockIdx.x * NT;
  sRows[t] = list[s * LCAP + row0 + t];
  __syncthreads();

  int wave = t >> 6, lane = t & 63;
  int l5 = lane >> 5, l31 = lane & 31;

  // staging sources: wave stages koct=wave; A rows j*64+lane, B col=lane
  int gj[4];
  #pragma unroll
  for (int j = 0; j < 4; ++j) {
    int v = sRows[j * 64 + lane];
    gj[j] = (v < 0) ? 0 : (v >> 6);
  }
  const u16* bh_src = w2h + ((size_t)s * 64 + lane) * H_ + wave * 8;
  const u16* bl_src = w2l + ((size_t)s * 64 + lane) * H_ + wave * 8;

  f32x16 acc[2][2];
  #pragma unroll
  for (int rt = 0; rt < 2; ++rt)
    #pragma unroll
    for (int ct = 0; ct < 2; ++ct) acc[rt][ct] = (f32x16)(0.f);

  for (int k0 = 0; k0 < H_; k0 += 32) {
    __syncthreads();
    #pragma unroll
    for (int j = 0; j < 4; ++j) {
      gload_lds16(hh + (size_t)gj[j] * H_ + k0 + wave * 8, &sAh[wave][j * 64][0]);
      gload_lds16(hl + (size_t)gj[j] * H_ + k0 + wave * 8, &sAl[wave][j * 64][0]);
    }
    gload_lds16(bh_src + k0, &sBh[wave][0][0]);
    gload_lds16(bl_src + k0, &sBl[wave][0][0]);
    __syncthreads();
    #pragma unroll
    for (int ks = 0; ks < 2; ++ks) {
      int ko = ks * 2 + l5;
      half8 ah[2], al[2], bh[2], bl[2];
      #pragma unroll
      for (int rt = 0; rt < 2; ++rt) {
        int r = wave * 64 + rt * 32 + l31;
        ah[rt] = *(const half8*)&sAh[ko][r][0];
        al[rt] = *(const half8*)&sAl[ko][r][0];
      }
      #pragma unroll
      for (int ct = 0; ct < 2; ++ct) {
        bh[ct] = *(const half8*)&sBh[ko][ct * 32 + l31][0];
        bl[ct] = *(const half8*)&sBl[ko][ct * 32 + l31][0];
      }
      #pragma unroll
      for (int rt = 0; rt < 2; ++rt)
        #pragma unroll
        for (int ct = 0; ct < 2; ++ct) {
          acc[rt][ct] = __builtin_amdgcn_mfma_f32_32x32x16_f16(al[rt], bh[ct], acc[rt][ct], 0, 0, 0);
          acc[rt][ct] = __builtin_amdgcn_mfma_f32_32x32x16_f16(ah[rt], bl[ct], acc[rt][ct], 0, 0, 0);
          acc[rt][ct] = __builtin_amdgcn_mfma_f32_32x32x16_f16(ah[rt], bh[ct], acc[rt][ct], 0, 0, 0);
        }
    }
  }

  const float invs = 1.0f / (SCALE_H * SCALE_W);
  #pragma unroll
  for (int ct = 0; ct < 2; ++ct) {
    int col = ct * 32 + l31;
    if (col >= NF) continue;
    float bias = b2[s * NF + col];
    #pragma unroll
    for (int rt = 0; rt < 2; ++rt) {
      #pragma unroll
      for (int reg = 0; reg < 16; ++reg) {
        int r = wave * 64 + rt * 32 + (reg & 3) + 8 * (reg >> 2) + 4 * l5;
        int v = sRows[r];
        if (v >= 0) {
          int g = v >> 6, p = v & 63;
          mats[(size_t)g * 2500 + p * NF + col] = acc[rt][ct][reg] * invs + bias;
        }
      }
    }
  }
}

// ---- K3: 50x50 LU det with partial pivoting, 1 wave per matrix ----
__global__ void k_det(const float* __restrict__ mats, float* __restrict__ detw,
                      float* __restrict__ out, int spin) {
  __shared__ float sA[4][NF * 52];
  int t = threadIdx.x;
  int wave = t >> 6, lane = t & 63;
  int mb = blockIdx.x * 4 + wave;
  const float* src = mats + (size_t)mb * 2500;
  float* sa = sA[wave];
  for (int i = lane; i < 2500; i += 64) {
    int r = i / 50, c = i - r * 50;
    sa[r * 52 + c] = src[i];
  }
  if (lane < NF) { sa[lane * 52 + 50] = 0.f; sa[lane * 52 + 51] = 0.f; }
  __syncthreads();

  float4 row[13];
  if (lane < NF) {
    const float4* rp = (const float4*)(sa + lane * 52);
    #pragma unroll
    for (int q = 0; q < 13; ++q) row[q] = rp[q];
  } else {
    #pragma unroll
    for (int q = 0; q < 13; ++q) row[q] = make_float4(0.f, 0.f, 0.f, 0.f);
  }

  double detd = 1.0;
  int parity = 0;
  int virt = lane;
  bool active = (lane < NF);
  #pragma unroll
  for (int p = 0; p < NF; ++p) {
    const int q_ = p >> 2, e_ = p & 3;
    float4 rq = row[q_];
    float cp = (e_ == 0) ? rq.x : (e_ == 1) ? rq.y : (e_ == 2) ? rq.z : rq.w;
    unsigned bits = __float_as_uint(fabsf(cp)) & 0xFFFFFFC0u;
    unsigned key = active ? (bits | (unsigned)lane) : 0u;
    #pragma unroll
    for (int mm = 32; mm >= 1; mm >>= 1) {
      unsigned o = (unsigned)__shfl_xor((int)key, mm);
      key = key > o ? key : o;
    }
    int pr = (int)(key & 63u);
    float v = __shfl(cp, pr);
    if (key < 64u) v = 0.f;
    detd *= (double)v;
    int vp = __shfl(virt, p);
    unsigned long long bal = __ballot(virt == pr);
    int l = __ffsll((long long)bal) - 1;
    parity ^= (l != p) ? 1 : 0;
    virt = (lane == p) ? pr : ((lane == l) ? vp : virt);
    float invv = (v != 0.f) ? (1.0f / v) : 0.f;
    float m = (active && lane != pr) ? (cp * invv) : 0.f;
    active = active && (lane != pr);
    #pragma unroll
    for (int q = (p + 1) >> 2; q < 13; ++q) {
      float4 pq;
      pq.x = __shfl(row[q].x, pr);
      pq.y = __shfl(row[q].y, pr);
      pq.z = __shfl(row[q].z, pr);
      pq.w = __shfl(row[q].w, pr);
      row[q].x = fmaf(-m, pq.x, row[q].x);
      row[q].y = fmaf(-m, pq.y, row[q].y);
      row[q].z = fmaf(-m, pq.z, row[q].z);
      row[q].w = fmaf(-m, pq.w, row[q].w);
    }
  }
  float det = (float)detd;
  if (parity) det = -det;
  if (lane == 0) {
    if (spin == 0) detw[mb] = det;
    else           out[mb]  = detw[mb] * det;
  }
}

extern "C" void kernel_launch(void* const* d_in, const int* in_sizes, int n_in,
                              void* d_out, int out_size, void* d_ws, size_t ws_size,
                              hipStream_t stream) {
  const float* cfg = (const float*)d_in[0];
  char* ws = (char*)d_ws;
  float* mats = (float*)ws;            ws += (size_t)B_ * 2500 * 4;
  u16*   hh   = (u16*)ws;              ws += (size_t)B_ * H_ * 2;
  u16*   hl   = (u16*)ws;              ws += (size_t)B_ * H_ * 2;
  u16*   w2h  = (u16*)ws;              ws += (size_t)S_ * 64 * H_ * 2;
  u16*   w2l  = (u16*)ws;              ws += (size_t)S_ * 64 * H_ * 2;
  int*   list = (int*)ws;              ws += (size_t)S_ * LCAP * 4;
  int*   cnt  = (int*)ws;              ws += 512;
  float* detw = (float*)ws;
  float* out  = (float*)d_out;

  for (int spin = 0; spin < 2; ++spin) {
    const float* W1 = (const float*)d_in[1 + spin * 4];
    const float* b1 = (const float*)d_in[2 + spin * 4];
    const float* W2 = (const float*)d_in[3 + spin * 4];
    const float* b2 = (const float*)d_in[4 + spin * 4];
    k_splitw2<<<dim3(S_, 8), 256, 0, stream>>>(W2, w2h, w2l, cnt);
    k_hidden <<<B_, 256, 0, stream>>>(cfg + spin * S_, W1, b1, hh, hl, list, cnt);
    k_pad    <<<S_, 256, 0, stream>>>(list, cnt);
    k_gemm   <<<dim3(LCAP / NT, S_), 256, 0, stream>>>(hh, hl, w2h, w2l, b2, list, cnt, mats);
    k_det    <<<B_ / 4, 256, 0, stream>>>(mats, detw, out, spin);
  }
}

// Round 6
// 645.711 us; speedup vs baseline: 5.0338x; 2.0144x over previous
//
#include <hip/hip_runtime.h>

// B=8192, S=100, H=512, NF=50 filled/spin. out[b] = det_up * det_dn.
// Regular dense GEMM over all rows x 5056 padded cols; rank-gathered epilogue.
//   k_prep  : W2 -> LDS-image slabs [spin][ntile][kc][ko][64][8] fp16 hi/lo (x4096)
//   k_hidden: h rows -> LDS-image slabs [spin][mtile][kc][ko][256][8] hi/lo (x256) + rank8
//   k_gemm  : 256x64 tile, dbuf 2-phase, 3-product split-fp16 MFMA, rank-write
//   k_det   : 50x50 LU, wave/matrix
// FIX vs round 5: global_load_lds source must be PER-LANE (guide m104/m173);
// added +lane*8 to ah_src/al_src/b_src. Round 5 passed wave-uniform sources,
// so every lane staged the same 16B -> garbage tiles.

#define B_   8192
#define S_   100
#define H_   512
#define NF   50
#define W2N  5000
#define NTN  79            // 64-col tiles over 5000 (+56 pad)
#define SCALE_H 256.0f
#define SCALE_W 4096.0f

typedef _Float16 half8 __attribute__((ext_vector_type(8)));
typedef float f32x16 __attribute__((ext_vector_type(16)));
typedef unsigned short u16;
typedef unsigned int u32;

__device__ __forceinline__ u16 f2h(float x) {
  _Float16 h = (_Float16)x;
  return __builtin_bit_cast(u16, h);
}
__device__ __forceinline__ float h2f(u16 u) {
  return (float)__builtin_bit_cast(_Float16, u);
}
__device__ __forceinline__ void gload16(const void* g, void* l) {
  __builtin_amdgcn_global_load_lds(
      reinterpret_cast<const __attribute__((address_space(1))) u32*>(
          reinterpret_cast<uintptr_t>(g)),
      reinterpret_cast<__attribute__((address_space(3))) u32*>(
          reinterpret_cast<uintptr_t>(l)),
      16, 0, 0);
}

// ---- K0: W2 -> w2{h,l}[spin][n][kc][ko][64][8], cols >=5000 zero ----
__global__ void k_prep(const float* __restrict__ W2u, const float* __restrict__ W2d,
                       u16* __restrict__ w2h, u16* __restrict__ w2l) {
  __shared__ u16 sHi[64 * 16], sLo[64 * 16];
  int n = blockIdx.x, kcg = blockIdx.y, spin = blockIdx.z, t = threadIdx.x;
  const float* W2 = spin ? W2d : W2u;
  size_t spBase = (size_t)spin * NTN * 32 * 2 * 512;
  int c = t & 63;
  int nc = n * 64 + c;
  for (int kc = kcg * 4; kc < kcg * 4 + 4; ++kc) {
    __syncthreads();
    #pragma unroll
    for (int q = 0; q < 4; ++q) {
      int kr = q * 4 + (t >> 6);
      float v = (nc < W2N) ? W2[(size_t)(kc * 16 + kr) * W2N + nc] * SCALE_W : 0.f;
      u16 hv = f2h(v);
      sHi[c * 16 + kr] = hv;
      sLo[c * 16 + kr] = f2h(v - h2f(hv));
    }
    __syncthreads();
    if (t < 128) {
      int ko = t >> 6, cc = t & 63;
      size_t off = spBase + (((size_t)n * 32 + kc) * 2 + ko) * 512 + cc * 8;
      *(uint4*)(w2h + off) = *(const uint4*)&sHi[cc * 16 + ko * 8];
      *(uint4*)(w2l + off) = *(const uint4*)&sLo[cc * 16 + ko * 8];
    }
  }
}

// ---- K1: ballot-rank + h = relu(sum W1 rows + b1) -> hk slabs + rank8 ----
__global__ void k_hidden(const float* __restrict__ cfg, const float* __restrict__ W1u,
                         const float* __restrict__ b1u, const float* __restrict__ W1d,
                         const float* __restrict__ b1d, u16* __restrict__ hk_h,
                         u16* __restrict__ hk_l, signed char* __restrict__ rank8) {
  __shared__ int sFilled[NF];
  __shared__ unsigned long long sM0;
  __shared__ u16 sHv[512], sLv[512];
  int b = blockIdx.x, spin = blockIdx.y, t = threadIdx.x;
  const float* W1 = spin ? W1d : W1u;
  const float* b1 = spin ? b1d : b1u;
  bool f = (t < S_) ? (cfg[(size_t)b * 200 + spin * 100 + t] > 0.5f) : false;
  unsigned long long m = __ballot(f);
  if (t == 0) sM0 = m;
  __syncthreads();
  int r = -1;
  if (f) {
    int lane = t & 63;
    int below = __popcll(m & ((1ULL << lane) - 1ULL));
    r = (t < 64) ? below : (__popcll(sM0) + below);
    sFilled[r] = t;
  }
  if (t < S_) rank8[((size_t)spin * B_ + b) * S_ + t] = (signed char)r;
  __syncthreads();
  float a0 = b1[t], a1 = b1[t + 256];
  #pragma unroll 5
  for (int i = 0; i < NF; ++i) {
    const float* w = W1 + (size_t)sFilled[i] * H_;
    a0 += w[t];
    a1 += w[t + 256];
  }
  a0 = fmaxf(a0, 0.f) * SCALE_H;
  a1 = fmaxf(a1, 0.f) * SCALE_H;
  u16 h0 = f2h(a0), h1 = f2h(a1);
  sHv[t] = h0;
  sHv[t + 256] = h1;
  sLv[t] = f2h(a0 - h2f(h0));
  sLv[t + 256] = f2h(a1 - h2f(h1));
  __syncthreads();
  int mtile = b >> 8, rr = b & 255;
  if (t < 128) {
    int arr = t >> 6;            // 0=hi 1=lo
    int chunk = t & 63;          // k-octet: kc = chunk>>1, ko = chunk&1
    int kc = chunk >> 1, ko = chunk & 1;
    size_t off = ((((size_t)spin * 32 + mtile) * 32 + kc) * 2 + ko) * 2048 + rr * 8;
    uint4 v = arr ? *(const uint4*)&sLv[chunk * 8] : *(const uint4*)&sHv[chunk * 8];
    *(uint4*)((arr ? hk_l : hk_h) + off) = v;
  }
}

// ---- K2: dense 256x64 GEMM, dbuf 2-phase, 3-product split fp16 ----
// grid (32 mtile, 79 ntile), block 256 = 4 waves, wave tile 64x64 (2x2 of 32x32).
__global__ void __launch_bounds__(256, 3)
k_gemm(const u16* __restrict__ hk_h, const u16* __restrict__ hk_l,
       const u16* __restrict__ w2h, const u16* __restrict__ w2l,
       const float* __restrict__ b2, const signed char* __restrict__ rank8,
       float* __restrict__ mats, int spin) {
  __shared__ __align__(16) u16 sAh[2][2][256][8];   // 16 KB
  __shared__ __align__(16) u16 sAl[2][2][256][8];   // 16 KB
  __shared__ __align__(16) u16 sBh[2][2][64][8];    // 4 KB
  __shared__ __align__(16) u16 sBl[2][2][64][8];    // 4 KB
  __shared__ int sRank[256][3];                     // 3 KB
  int t = threadIdx.x, wave = t >> 6, lane = t & 63;
  int l5 = lane >> 5, l31 = lane & 31;
  int mtile = blockIdx.x, n = blockIdx.y;
  int m0 = mtile * 256, n0 = n * 64;
  int s0 = n0 / 50;

  #pragma unroll
  for (int i = 0; i < 3; ++i) {
    int s = s0 + i;
    sRank[t][i] = (s < S_) ? (int)rank8[((size_t)spin * B_ + m0 + t) * S_ + s] : -1;
  }

  // per-lane global sources: lane l stages row/col l of its wave's 64-slab
  const u16* ah_src = hk_h + (((size_t)spin * 32 + mtile) * 32) * 2 * 2048 +
                      wave * 64 * 8 + lane * 8;
  const u16* al_src = hk_l + (((size_t)spin * 32 + mtile) * 32) * 2 * 2048 +
                      wave * 64 * 8 + lane * 8;
  const u16* b_src  = (wave < 2 ? w2h : w2l) +
                      ((size_t)spin * NTN + n) * 32 * 2 * 512 + (wave & 1) * 512 +
                      lane * 8;

  f32x16 acc[2][2];
  #pragma unroll
  for (int rt = 0; rt < 2; ++rt)
    #pragma unroll
    for (int ct = 0; ct < 2; ++ct) acc[rt][ct] = (f32x16)(0.f);

  // STAGE(buf, kc): 4 A-gloads + 1 B-gload per wave, all linear 1KB/wave
  #define STAGE(buf, kc)                                                      \
    do {                                                                      \
      size_t ao = (size_t)(kc) * 2 * 2048;                                    \
      gload16(ah_src + ao,        &sAh[buf][0][wave * 64][0]);                \
      gload16(ah_src + ao + 2048, &sAh[buf][1][wave * 64][0]);                \
      gload16(al_src + ao,        &sAl[buf][0][wave * 64][0]);                \
      gload16(al_src + ao + 2048, &sAl[buf][1][wave * 64][0]);                \
      gload16(b_src + (size_t)(kc) * 1024,                                    \
              wave < 2 ? &sBh[buf][wave & 1][0][0] : &sBl[buf][wave & 1][0][0]); \
    } while (0)

  #define COMPUTE(buf)                                                        \
    do {                                                                      \
      half8 ah[2], al[2], bh[2], bl[2];                                       \
      _Pragma("unroll")                                                       \
      for (int rt = 0; rt < 2; ++rt) {                                        \
        ah[rt] = *(const half8*)&sAh[buf][l5][wave * 64 + rt * 32 + l31][0];  \
        al[rt] = *(const half8*)&sAl[buf][l5][wave * 64 + rt * 32 + l31][0];  \
      }                                                                       \
      _Pragma("unroll")                                                       \
      for (int ct = 0; ct < 2; ++ct) {                                        \
        bh[ct] = *(const half8*)&sBh[buf][l5][ct * 32 + l31][0];              \
        bl[ct] = *(const half8*)&sBl[buf][l5][ct * 32 + l31][0];              \
      }                                                                       \
      _Pragma("unroll")                                                       \
      for (int rt = 0; rt < 2; ++rt)                                          \
        _Pragma("unroll")                                                     \
        for (int ct = 0; ct < 2; ++ct) {                                      \
          acc[rt][ct] = __builtin_amdgcn_mfma_f32_32x32x16_f16(al[rt], bh[ct], acc[rt][ct], 0, 0, 0); \
          acc[rt][ct] = __builtin_amdgcn_mfma_f32_32x32x16_f16(ah[rt], bl[ct], acc[rt][ct], 0, 0, 0); \
          acc[rt][ct] = __builtin_amdgcn_mfma_f32_32x32x16_f16(ah[rt], bh[ct], acc[rt][ct], 0, 0, 0); \
        }                                                                     \
    } while (0)

  STAGE(0, 0);
  __syncthreads();
  int cur = 0;
  for (int kc = 0; kc < 31; ++kc) {
    STAGE(cur ^ 1, kc + 1);
    COMPUTE(cur);
    __syncthreads();
    cur ^= 1;
  }
  COMPUTE(cur);

  const float invs = 1.0f / (SCALE_H * SCALE_W);
  #pragma unroll
  for (int ct = 0; ct < 2; ++ct) {
    int nc = n0 + ct * 32 + l31;
    if (nc < W2N) {
      int s = nc / 50;
      int j = nc - s * 50;
      int si = s - s0;
      float bias = b2[nc];
      #pragma unroll
      for (int rt = 0; rt < 2; ++rt) {
        #pragma unroll
        for (int reg = 0; reg < 16; ++reg) {
          int rr = wave * 64 + rt * 32 + (reg & 3) + 8 * (reg >> 2) + 4 * l5;
          int p = sRank[rr][si];
          if (p >= 0)
            mats[(size_t)(m0 + rr) * 2500 + p * 50 + j] = acc[rt][ct][reg] * invs + bias;
        }
      }
    }
  }
  #undef STAGE
  #undef COMPUTE
}

// ---- K3: 50x50 LU det with partial pivoting, 1 wave per matrix ----
__global__ void k_det(const float* __restrict__ mats, float* __restrict__ detw,
                      float* __restrict__ out, int spin) {
  __shared__ float sA[4][NF * 52];
  int t = threadIdx.x;
  int wave = t >> 6, lane = t & 63;
  int mb = blockIdx.x * 4 + wave;
  const float* src = mats + (size_t)mb * 2500;
  float* sa = sA[wave];
  for (int i = lane; i < 2500; i += 64) {
    int r = i / 50, c = i - r * 50;
    sa[r * 52 + c] = src[i];
  }
  if (lane < NF) { sa[lane * 52 + 50] = 0.f; sa[lane * 52 + 51] = 0.f; }
  __syncthreads();

  float4 row[13];
  if (lane < NF) {
    const float4* rp = (const float4*)(sa + lane * 52);
    #pragma unroll
    for (int q = 0; q < 13; ++q) row[q] = rp[q];
  } else {
    #pragma unroll
    for (int q = 0; q < 13; ++q) row[q] = make_float4(0.f, 0.f, 0.f, 0.f);
  }

  double detd = 1.0;
  int parity = 0;
  int virt = lane;
  bool active = (lane < NF);
  #pragma unroll
  for (int p = 0; p < NF; ++p) {
    const int q_ = p >> 2, e_ = p & 3;
    float4 rq = row[q_];
    float cp = (e_ == 0) ? rq.x : (e_ == 1) ? rq.y : (e_ == 2) ? rq.z : rq.w;
    unsigned bits = __float_as_uint(fabsf(cp)) & 0xFFFFFFC0u;
    unsigned key = active ? (bits | (unsigned)lane) : 0u;
    #pragma unroll
    for (int mm = 32; mm >= 1; mm >>= 1) {
      unsigned o = (unsigned)__shfl_xor((int)key, mm);
      key = key > o ? key : o;
    }
    int pr = (int)(key & 63u);
    float v = __shfl(cp, pr);
    if (key < 64u) v = 0.f;
    detd *= (double)v;
    int vp = __shfl(virt, p);
    unsigned long long bal = __ballot(virt == pr);
    int l = __ffsll((long long)bal) - 1;
    parity ^= (l != p) ? 1 : 0;
    virt = (lane == p) ? pr : ((lane == l) ? vp : virt);
    float invv = (v != 0.f) ? (1.0f / v) : 0.f;
    float mlt = (active && lane != pr) ? (cp * invv) : 0.f;
    active = active && (lane != pr);
    #pragma unroll
    for (int q = (p + 1) >> 2; q < 13; ++q) {
      float4 pq;
      pq.x = __shfl(row[q].x, pr);
      pq.y = __shfl(row[q].y, pr);
      pq.z = __shfl(row[q].z, pr);
      pq.w = __shfl(row[q].w, pr);
      row[q].x = fmaf(-mlt, pq.x, row[q].x);
      row[q].y = fmaf(-mlt, pq.y, row[q].y);
      row[q].z = fmaf(-mlt, pq.z, row[q].z);
      row[q].w = fmaf(-mlt, pq.w, row[q].w);
    }
  }
  float det = (float)detd;
  if (parity) det = -det;
  if (lane == 0) {
    if (spin == 0) detw[mb] = det;
    else           out[mb]  = detw[mb] * det;
  }
}

extern "C" void kernel_launch(void* const* d_in, const int* in_sizes, int n_in,
                              void* d_out, int out_size, void* d_ws, size_t ws_size,
                              hipStream_t stream) {
  const float* cfg = (const float*)d_in[0];
  const float* W1u = (const float*)d_in[1];
  const float* b1u = (const float*)d_in[2];
  const float* W2u = (const float*)d_in[3];
  const float* b2u = (const float*)d_in[4];
  const float* W1d = (const float*)d_in[5];
  const float* b1d = (const float*)d_in[6];
  const float* W2d = (const float*)d_in[7];
  const float* b2d = (const float*)d_in[8];

  char* ws = (char*)d_ws;
  float* mats = (float*)ws;                 ws += (size_t)B_ * 2500 * 4;       // 81.9 MB
  u16*   hk_h = (u16*)ws;                   ws += (size_t)2 * B_ * H_ * 2;     // 16.8 MB
  u16*   hk_l = (u16*)ws;                   ws += (size_t)2 * B_ * H_ * 2;     // 16.8 MB
  u16*   w2h  = (u16*)ws;                   ws += (size_t)2 * NTN * 32 * 2 * 512 * 2; // 10.35 MB
  u16*   w2l  = (u16*)ws;                   ws += (size_t)2 * NTN * 32 * 2 * 512 * 2; // 10.35 MB
  signed char* rank8 = (signed char*)ws;    ws += (size_t)2 * B_ * S_;         // 1.64 MB
  float* detw = (float*)ws;
  float* out  = (float*)d_out;

  k_prep  <<<dim3(NTN, 8, 2), 256, 0, stream>>>(W2u, W2d, w2h, w2l);
  k_hidden<<<dim3(B_, 2), 256, 0, stream>>>(cfg, W1u, b1u, W1d, b1d, hk_h, hk_l, rank8);
  for (int spin = 0; spin < 2; ++spin) {
    const float* b2 = spin ? b2d : b2u;
    k_gemm<<<dim3(32, NTN), 256, 0, stream>>>(hk_h, hk_l, w2h, w2l, b2, rank8, mats, spin);
    k_det <<<B_ / 4, 256, 0, stream>>>(mats, detw, out, spin);
  }
}

// Round 7
// 643.334 us; speedup vs baseline: 5.0524x; 1.0037x over previous
//
#include <hip/hip_runtime.h>

// B=8192, S=100, H=512, NF=50 filled/spin. out[b] = det_up * det_dn.
//   k_prep  : W2 -> LDS-image slabs [spin][ntile][kc][ko][64][8] fp16 hi/lo (x4096)
//   k_hidden: h rows -> LDS-image slabs [spin][mtile][kc][ko][256][8] hi/lo (x256) + rank8
//   k_gemm  : 256x64 tile, dbuf 2-phase, 3-product split-fp16 MFMA, rank-write
//   k_det   : 50x50 LU, wave/matrix, LDS-free (direct per-lane row loads)
// mats layout: row stride 52 floats (16B-aligned rows), matrix stride 2600.

#define B_   8192
#define S_   100
#define H_   512
#define NF   50
#define W2N  5000
#define NTN  79            // 64-col tiles over 5000 (+56 pad)
#define MROW 52            // padded mats row stride (floats)
#define MMAT 2600          // padded mats matrix stride (floats)
#define SCALE_H 256.0f
#define SCALE_W 4096.0f

typedef _Float16 half8 __attribute__((ext_vector_type(8)));
typedef float f32x16 __attribute__((ext_vector_type(16)));
typedef unsigned short u16;
typedef unsigned int u32;

__device__ __forceinline__ u16 f2h(float x) {
  _Float16 h = (_Float16)x;
  return __builtin_bit_cast(u16, h);
}
__device__ __forceinline__ float h2f(u16 u) {
  return (float)__builtin_bit_cast(_Float16, u);
}
__device__ __forceinline__ void gload16(const void* g, void* l) {
  __builtin_amdgcn_global_load_lds(
      reinterpret_cast<const __attribute__((address_space(1))) u32*>(
          reinterpret_cast<uintptr_t>(g)),
      reinterpret_cast<__attribute__((address_space(3))) u32*>(
          reinterpret_cast<uintptr_t>(l)),
      16, 0, 0);
}

// ---- K0: W2 -> w2{h,l}[spin][n][kc][ko][64][8], cols >=5000 zero ----
__global__ void k_prep(const float* __restrict__ W2u, const float* __restrict__ W2d,
                       u16* __restrict__ w2h, u16* __restrict__ w2l) {
  __shared__ u16 sHi[64 * 16], sLo[64 * 16];
  int n = blockIdx.x, kcg = blockIdx.y, spin = blockIdx.z, t = threadIdx.x;
  const float* W2 = spin ? W2d : W2u;
  size_t spBase = (size_t)spin * NTN * 32 * 2 * 512;
  int c = t & 63;
  int nc = n * 64 + c;
  for (int kc = kcg * 4; kc < kcg * 4 + 4; ++kc) {
    __syncthreads();
    #pragma unroll
    for (int q = 0; q < 4; ++q) {
      int kr = q * 4 + (t >> 6);
      float v = (nc < W2N) ? W2[(size_t)(kc * 16 + kr) * W2N + nc] * SCALE_W : 0.f;
      u16 hv = f2h(v);
      sHi[c * 16 + kr] = hv;
      sLo[c * 16 + kr] = f2h(v - h2f(hv));
    }
    __syncthreads();
    if (t < 128) {
      int ko = t >> 6, cc = t & 63;
      size_t off = spBase + (((size_t)n * 32 + kc) * 2 + ko) * 512 + cc * 8;
      *(uint4*)(w2h + off) = *(const uint4*)&sHi[cc * 16 + ko * 8];
      *(uint4*)(w2l + off) = *(const uint4*)&sLo[cc * 16 + ko * 8];
    }
  }
}

// ---- K1: ballot-rank + h = relu(sum W1 rows + b1) -> hk slabs + rank8 ----
__global__ void k_hidden(const float* __restrict__ cfg, const float* __restrict__ W1u,
                         const float* __restrict__ b1u, const float* __restrict__ W1d,
                         const float* __restrict__ b1d, u16* __restrict__ hk_h,
                         u16* __restrict__ hk_l, signed char* __restrict__ rank8) {
  __shared__ int sFilled[NF];
  __shared__ unsigned long long sM0;
  __shared__ u16 sHv[512], sLv[512];
  int b = blockIdx.x, spin = blockIdx.y, t = threadIdx.x;
  const float* W1 = spin ? W1d : W1u;
  const float* b1 = spin ? b1d : b1u;
  bool f = (t < S_) ? (cfg[(size_t)b * 200 + spin * 100 + t] > 0.5f) : false;
  unsigned long long m = __ballot(f);
  if (t == 0) sM0 = m;
  __syncthreads();
  int r = -1;
  if (f) {
    int lane = t & 63;
    int below = __popcll(m & ((1ULL << lane) - 1ULL));
    r = (t < 64) ? below : (__popcll(sM0) + below);
    sFilled[r] = t;
  }
  if (t < S_) rank8[((size_t)spin * B_ + b) * S_ + t] = (signed char)r;
  __syncthreads();
  float a0 = b1[t], a1 = b1[t + 256];
  #pragma unroll 5
  for (int i = 0; i < NF; ++i) {
    const float* w = W1 + (size_t)sFilled[i] * H_;
    a0 += w[t];
    a1 += w[t + 256];
  }
  a0 = fmaxf(a0, 0.f) * SCALE_H;
  a1 = fmaxf(a1, 0.f) * SCALE_H;
  u16 h0 = f2h(a0), h1 = f2h(a1);
  sHv[t] = h0;
  sHv[t + 256] = h1;
  sLv[t] = f2h(a0 - h2f(h0));
  sLv[t + 256] = f2h(a1 - h2f(h1));
  __syncthreads();
  int mtile = b >> 8, rr = b & 255;
  if (t < 128) {
    int arr = t >> 6;            // 0=hi 1=lo
    int chunk = t & 63;          // k-octet: kc = chunk>>1, ko = chunk&1
    int kc = chunk >> 1, ko = chunk & 1;
    size_t off = ((((size_t)spin * 32 + mtile) * 32 + kc) * 2 + ko) * 2048 + rr * 8;
    uint4 v = arr ? *(const uint4*)&sLv[chunk * 8] : *(const uint4*)&sHv[chunk * 8];
    *(uint4*)((arr ? hk_l : hk_h) + off) = v;
  }
}

// ---- K2: dense 256x64 GEMM, dbuf 2-phase, 3-product split fp16 ----
// grid (32 mtile, 79 ntile), block 256 = 4 waves, wave tile 64x64 (2x2 of 32x32).
__global__ void __launch_bounds__(256, 3)
k_gemm(const u16* __restrict__ hk_h, const u16* __restrict__ hk_l,
       const u16* __restrict__ w2h, const u16* __restrict__ w2l,
       const float* __restrict__ b2, const signed char* __restrict__ rank8,
       float* __restrict__ mats, int spin) {
  __shared__ __align__(16) u16 sAh[2][2][256][8];   // 16 KB
  __shared__ __align__(16) u16 sAl[2][2][256][8];   // 16 KB
  __shared__ __align__(16) u16 sBh[2][2][64][8];    // 4 KB
  __shared__ __align__(16) u16 sBl[2][2][64][8];    // 4 KB
  __shared__ int sRank[256][3];                     // 3 KB
  int t = threadIdx.x, wave = t >> 6, lane = t & 63;
  int l5 = lane >> 5, l31 = lane & 31;
  int mtile = blockIdx.x, n = blockIdx.y;
  int m0 = mtile * 256, n0 = n * 64;
  int s0 = n0 / 50;

  #pragma unroll
  for (int i = 0; i < 3; ++i) {
    int s = s0 + i;
    sRank[t][i] = (s < S_) ? (int)rank8[((size_t)spin * B_ + m0 + t) * S_ + s] : -1;
  }

  // per-lane global sources: lane l stages row/col l of its wave's 64-slab
  const u16* ah_src = hk_h + (((size_t)spin * 32 + mtile) * 32) * 2 * 2048 +
                      wave * 64 * 8 + lane * 8;
  const u16* al_src = hk_l + (((size_t)spin * 32 + mtile) * 32) * 2 * 2048 +
                      wave * 64 * 8 + lane * 8;
  const u16* b_src  = (wave < 2 ? w2h : w2l) +
                      ((size_t)spin * NTN + n) * 32 * 2 * 512 + (wave & 1) * 512 +
                      lane * 8;

  f32x16 acc[2][2];
  #pragma unroll
  for (int rt = 0; rt < 2; ++rt)
    #pragma unroll
    for (int ct = 0; ct < 2; ++ct) acc[rt][ct] = (f32x16)(0.f);

  // STAGE(buf, kc): 4 A-gloads + 1 B-gload per wave, all linear 1KB/wave
  #define STAGE(buf, kc)                                                      \
    do {                                                                      \
      size_t ao = (size_t)(kc) * 2 * 2048;                                    \
      gload16(ah_src + ao,        &sAh[buf][0][wave * 64][0]);                \
      gload16(ah_src + ao + 2048, &sAh[buf][1][wave * 64][0]);                \
      gload16(al_src + ao,        &sAl[buf][0][wave * 64][0]);                \
      gload16(al_src + ao + 2048, &sAl[buf][1][wave * 64][0]);                \
      gload16(b_src + (size_t)(kc) * 1024,                                    \
              wave < 2 ? &sBh[buf][wave & 1][0][0] : &sBl[buf][wave & 1][0][0]); \
    } while (0)

  #define COMPUTE(buf)                                                        \
    do {                                                                      \
      half8 ah[2], al[2], bh[2], bl[2];                                       \
      _Pragma("unroll")                                                       \
      for (int rt = 0; rt < 2; ++rt) {                                        \
        ah[rt] = *(const half8*)&sAh[buf][l5][wave * 64 + rt * 32 + l31][0];  \
        al[rt] = *(const half8*)&sAl[buf][l5][wave * 64 + rt * 32 + l31][0];  \
      }                                                                       \
      _Pragma("unroll")                                                       \
      for (int ct = 0; ct < 2; ++ct) {                                        \
        bh[ct] = *(const half8*)&sBh[buf][l5][ct * 32 + l31][0];              \
        bl[ct] = *(const half8*)&sBl[buf][l5][ct * 32 + l31][0];              \
      }                                                                       \
      _Pragma("unroll")                                                       \
      for (int rt = 0; rt < 2; ++rt)                                          \
        _Pragma("unroll")                                                     \
        for (int ct = 0; ct < 2; ++ct) {                                      \
          acc[rt][ct] = __builtin_amdgcn_mfma_f32_32x32x16_f16(al[rt], bh[ct], acc[rt][ct], 0, 0, 0); \
          acc[rt][ct] = __builtin_amdgcn_mfma_f32_32x32x16_f16(ah[rt], bl[ct], acc[rt][ct], 0, 0, 0); \
          acc[rt][ct] = __builtin_amdgcn_mfma_f32_32x32x16_f16(ah[rt], bh[ct], acc[rt][ct], 0, 0, 0); \
        }                                                                     \
    } while (0)

  STAGE(0, 0);
  __syncthreads();
  int cur = 0;
  for (int kc = 0; kc < 31; ++kc) {
    STAGE(cur ^ 1, kc + 1);
    COMPUTE(cur);
    __syncthreads();
    cur ^= 1;
  }
  COMPUTE(cur);

  const float invs = 1.0f / (SCALE_H * SCALE_W);
  #pragma unroll
  for (int ct = 0; ct < 2; ++ct) {
    int nc = n0 + ct * 32 + l31;
    if (nc < W2N) {
      int s = nc / 50;
      int j = nc - s * 50;
      int si = s - s0;
      float bias = b2[nc];
      #pragma unroll
      for (int rt = 0; rt < 2; ++rt) {
        #pragma unroll
        for (int reg = 0; reg < 16; ++reg) {
          int rr = wave * 64 + rt * 32 + (reg & 3) + 8 * (reg >> 2) + 4 * l5;
          int p = sRank[rr][si];
          if (p >= 0)
            mats[(size_t)(m0 + rr) * MMAT + p * MROW + j] = acc[rt][ct][reg] * invs + bias;
        }
      }
    }
  }
  #undef STAGE
  #undef COMPUTE
}

// ---- K3: 50x50 LU det with partial pivoting, 1 wave per matrix, LDS-free ----
__global__ void __launch_bounds__(256, 8)
k_det(const float* __restrict__ mats, float* __restrict__ detw,
      float* __restrict__ out, int spin) {
  int t = threadIdx.x;
  int wave = t >> 6, lane = t & 63;
  int mb = blockIdx.x * 4 + wave;

  float4 row[13];
  if (lane < NF) {
    const float4* rp = (const float4*)(mats + (size_t)mb * MMAT + lane * MROW);
    #pragma unroll
    for (int q = 0; q < 13; ++q) row[q] = rp[q];
    row[12].z = 0.f;      // pad cols 50,51 (garbage in memory)
    row[12].w = 0.f;
  } else {
    #pragma unroll
    for (int q = 0; q < 13; ++q) row[q] = make_float4(0.f, 0.f, 0.f, 0.f);
  }

  double detd = 1.0;
  int parity = 0;
  int virt = lane;
  bool active = (lane < NF);
  #pragma unroll
  for (int p = 0; p < NF; ++p) {
    const int q_ = p >> 2, e_ = p & 3;
    float4 rq = row[q_];
    float cp = (e_ == 0) ? rq.x : (e_ == 1) ? rq.y : (e_ == 2) ? rq.z : rq.w;
    unsigned bits = __float_as_uint(fabsf(cp)) & 0xFFFFFFC0u;
    unsigned key = active ? (bits | (unsigned)lane) : 0u;
    #pragma unroll
    for (int mm = 32; mm >= 1; mm >>= 1) {
      unsigned o = (unsigned)__shfl_xor((int)key, mm);
      key = key > o ? key : o;
    }
    int pr = (int)(key & 63u);
    float v = __shfl(cp, pr);
    if (key < 64u) v = 0.f;
    detd *= (double)v;
    int vp = __shfl(virt, p);
    unsigned long long bal = __ballot(virt == pr);
    int l = __ffsll((long long)bal) - 1;
    parity ^= (l != p) ? 1 : 0;
    virt = (lane == p) ? pr : ((lane == l) ? vp : virt);
    float invv = (v != 0.f) ? (1.0f / v) : 0.f;
    float mlt = (active && lane != pr) ? (cp * invv) : 0.f;
    active = active && (lane != pr);
    #pragma unroll
    for (int q = (p + 1) >> 2; q < 13; ++q) {
      float4 pq;
      pq.x = __shfl(row[q].x, pr);
      pq.y = __shfl(row[q].y, pr);
      pq.z = __shfl(row[q].z, pr);
      pq.w = __shfl(row[q].w, pr);
      row[q].x = fmaf(-mlt, pq.x, row[q].x);
      row[q].y = fmaf(-mlt, pq.y, row[q].y);
      row[q].z = fmaf(-mlt, pq.z, row[q].z);
      row[q].w = fmaf(-mlt, pq.w, row[q].w);
    }
  }
  float det = (float)detd;
  if (parity) det = -det;
  if (lane == 0) {
    if (spin == 0) detw[mb] = det;
    else           out[mb]  = detw[mb] * det;
  }
}

extern "C" void kernel_launch(void* const* d_in, const int* in_sizes, int n_in,
                              void* d_out, int out_size, void* d_ws, size_t ws_size,
                              hipStream_t stream) {
  const float* cfg = (const float*)d_in[0];
  const float* W1u = (const float*)d_in[1];
  const float* b1u = (const float*)d_in[2];
  const float* W2u = (const float*)d_in[3];
  const float* b2u = (const float*)d_in[4];
  const float* W1d = (const float*)d_in[5];
  const float* b1d = (const float*)d_in[6];
  const float* W2d = (const float*)d_in[7];
  const float* b2d = (const float*)d_in[8];

  char* ws = (char*)d_ws;
  float* mats = (float*)ws;                 ws += (size_t)B_ * MMAT * 4;       // 85.2 MB
  u16*   hk_h = (u16*)ws;                   ws += (size_t)2 * B_ * H_ * 2;     // 16.8 MB
  u16*   hk_l = (u16*)ws;                   ws += (size_t)2 * B_ * H_ * 2;     // 16.8 MB
  u16*   w2h  = (u16*)ws;                   ws += (size_t)2 * NTN * 32 * 2 * 512 * 2; // 10.35 MB
  u16*   w2l  = (u16*)ws;                   ws += (size_t)2 * NTN * 32 * 2 * 512 * 2; // 10.35 MB
  signed char* rank8 = (signed char*)ws;    ws += (size_t)2 * B_ * S_;         // 1.64 MB
  float* detw = (float*)ws;
  float* out  = (float*)d_out;

  k_prep  <<<dim3(NTN, 8, 2), 256, 0, stream>>>(W2u, W2d, w2h, w2l);
  k_hidden<<<dim3(B_, 2), 256, 0, stream>>>(cfg, W1u, b1u, W1d, b1d, hk_h, hk_l, rank8);
  for (int spin = 0; spin < 2; ++spin) {
    const float* b2 = spin ? b2d : b2u;
    k_gemm<<<dim3(32, NTN), 256, 0, stream>>>(hk_h, hk_l, w2h, w2l, b2, rank8, mats, spin);
    k_det <<<B_ / 4, 256, 0, stream>>>(mats, detw, out, spin);
  }
}

// Round 8
// 520.615 us; speedup vs baseline: 6.2433x; 1.2357x over previous
//
#include <hip/hip_runtime.h>

// B=8192, S=100, H=512, NF=50 filled/spin. out[b] = det_up * det_dn.
//   k_prep  : W2 -> LDS-image slabs [spin][ntile][kc][ko][64][8] fp16 hi/lo (x4096)
//   k_hidden: h rows -> LDS-image slabs [spin][mtile][kc][ko][256][8] hi/lo (x256) + rank8
//   k_gemm  : 256x64 tile, dbuf 2-phase, 3-product split-fp16 MFMA, rank-write
//   k_det   : 50x50 LU, wave/matrix, LDS-free; pivot broadcast via v_readlane
//             (wave-uniform pivot index in SGPR -> zero DS ops in elimination;
//              round-7 lesson: shfl=ds_bpermute saturated the per-CU DS pipe)
// mats layout: row stride 52 floats (16B-aligned rows), matrix stride 2600.

#define B_   8192
#define S_   100
#define H_   512
#define NF   50
#define W2N  5000
#define NTN  79            // 64-col tiles over 5000 (+56 pad)
#define MROW 52            // padded mats row stride (floats)
#define MMAT 2600          // padded mats matrix stride (floats)
#define SCALE_H 256.0f
#define SCALE_W 4096.0f

typedef _Float16 half8 __attribute__((ext_vector_type(8)));
typedef float f32x16 __attribute__((ext_vector_type(16)));
typedef unsigned short u16;
typedef unsigned int u32;

__device__ __forceinline__ u16 f2h(float x) {
  _Float16 h = (_Float16)x;
  return __builtin_bit_cast(u16, h);
}
__device__ __forceinline__ float h2f(u16 u) {
  return (float)__builtin_bit_cast(_Float16, u);
}
__device__ __forceinline__ void gload16(const void* g, void* l) {
  __builtin_amdgcn_global_load_lds(
      reinterpret_cast<const __attribute__((address_space(1))) u32*>(
          reinterpret_cast<uintptr_t>(g)),
      reinterpret_cast<__attribute__((address_space(3))) u32*>(
          reinterpret_cast<uintptr_t>(l)),
      16, 0, 0);
}
__device__ __forceinline__ float rlane(float x, int sl) {
  return __builtin_bit_cast(float,
      __builtin_amdgcn_readlane(__builtin_bit_cast(int, x), sl));
}

// ---- K0: W2 -> w2{h,l}[spin][n][kc][ko][64][8], cols >=5000 zero ----
__global__ void k_prep(const float* __restrict__ W2u, const float* __restrict__ W2d,
                       u16* __restrict__ w2h, u16* __restrict__ w2l) {
  __shared__ u16 sHi[64 * 16], sLo[64 * 16];
  int n = blockIdx.x, kcg = blockIdx.y, spin = blockIdx.z, t = threadIdx.x;
  const float* W2 = spin ? W2d : W2u;
  size_t spBase = (size_t)spin * NTN * 32 * 2 * 512;
  int c = t & 63;
  int nc = n * 64 + c;
  for (int kc = kcg * 4; kc < kcg * 4 + 4; ++kc) {
    __syncthreads();
    #pragma unroll
    for (int q = 0; q < 4; ++q) {
      int kr = q * 4 + (t >> 6);
      float v = (nc < W2N) ? W2[(size_t)(kc * 16 + kr) * W2N + nc] * SCALE_W : 0.f;
      u16 hv = f2h(v);
      sHi[c * 16 + kr] = hv;
      sLo[c * 16 + kr] = f2h(v - h2f(hv));
    }
    __syncthreads();
    if (t < 128) {
      int ko = t >> 6, cc = t & 63;
      size_t off = spBase + (((size_t)n * 32 + kc) * 2 + ko) * 512 + cc * 8;
      *(uint4*)(w2h + off) = *(const uint4*)&sHi[cc * 16 + ko * 8];
      *(uint4*)(w2l + off) = *(const uint4*)&sLo[cc * 16 + ko * 8];
    }
  }
}

// ---- K1: ballot-rank + h = relu(sum W1 rows + b1) -> hk slabs + rank8 ----
__global__ void k_hidden(const float* __restrict__ cfg, const float* __restrict__ W1u,
                         const float* __restrict__ b1u, const float* __restrict__ W1d,
                         const float* __restrict__ b1d, u16* __restrict__ hk_h,
                         u16* __restrict__ hk_l, signed char* __restrict__ rank8) {
  __shared__ int sFilled[NF];
  __shared__ unsigned long long sM0;
  __shared__ u16 sHv[512], sLv[512];
  int b = blockIdx.x, spin = blockIdx.y, t = threadIdx.x;
  const float* W1 = spin ? W1d : W1u;
  const float* b1 = spin ? b1d : b1u;
  bool f = (t < S_) ? (cfg[(size_t)b * 200 + spin * 100 + t] > 0.5f) : false;
  unsigned long long m = __ballot(f);
  if (t == 0) sM0 = m;
  __syncthreads();
  int r = -1;
  if (f) {
    int lane = t & 63;
    int below = __popcll(m & ((1ULL << lane) - 1ULL));
    r = (t < 64) ? below : (__popcll(sM0) + below);
    sFilled[r] = t;
  }
  if (t < S_) rank8[((size_t)spin * B_ + b) * S_ + t] = (signed char)r;
  __syncthreads();
  float a0 = b1[t], a1 = b1[t + 256];
  #pragma unroll 5
  for (int i = 0; i < NF; ++i) {
    const float* w = W1 + (size_t)sFilled[i] * H_;
    a0 += w[t];
    a1 += w[t + 256];
  }
  a0 = fmaxf(a0, 0.f) * SCALE_H;
  a1 = fmaxf(a1, 0.f) * SCALE_H;
  u16 h0 = f2h(a0), h1 = f2h(a1);
  sHv[t] = h0;
  sHv[t + 256] = h1;
  sLv[t] = f2h(a0 - h2f(h0));
  sLv[t + 256] = f2h(a1 - h2f(h1));
  __syncthreads();
  int mtile = b >> 8, rr = b & 255;
  if (t < 128) {
    int arr = t >> 6;            // 0=hi 1=lo
    int chunk = t & 63;          // k-octet: kc = chunk>>1, ko = chunk&1
    int kc = chunk >> 1, ko = chunk & 1;
    size_t off = ((((size_t)spin * 32 + mtile) * 32 + kc) * 2 + ko) * 2048 + rr * 8;
    uint4 v = arr ? *(const uint4*)&sLv[chunk * 8] : *(const uint4*)&sHv[chunk * 8];
    *(uint4*)((arr ? hk_l : hk_h) + off) = v;
  }
}

// ---- K2: dense 256x64 GEMM, dbuf 2-phase, 3-product split fp16 ----
// grid (32 mtile, 79 ntile), block 256 = 4 waves, wave tile 64x64 (2x2 of 32x32).
__global__ void __launch_bounds__(256, 3)
k_gemm(const u16* __restrict__ hk_h, const u16* __restrict__ hk_l,
       const u16* __restrict__ w2h, const u16* __restrict__ w2l,
       const float* __restrict__ b2, const signed char* __restrict__ rank8,
       float* __restrict__ mats, int spin) {
  __shared__ __align__(16) u16 sAh[2][2][256][8];   // 16 KB
  __shared__ __align__(16) u16 sAl[2][2][256][8];   // 16 KB
  __shared__ __align__(16) u16 sBh[2][2][64][8];    // 4 KB
  __shared__ __align__(16) u16 sBl[2][2][64][8];    // 4 KB
  __shared__ int sRank[256][3];                     // 3 KB
  int t = threadIdx.x, wave = t >> 6, lane = t & 63;
  int l5 = lane >> 5, l31 = lane & 31;
  int mtile = blockIdx.x, n = blockIdx.y;
  int m0 = mtile * 256, n0 = n * 64;
  int s0 = n0 / 50;

  #pragma unroll
  for (int i = 0; i < 3; ++i) {
    int s = s0 + i;
    sRank[t][i] = (s < S_) ? (int)rank8[((size_t)spin * B_ + m0 + t) * S_ + s] : -1;
  }

  // per-lane global sources: lane l stages row/col l of its wave's 64-slab
  const u16* ah_src = hk_h + (((size_t)spin * 32 + mtile) * 32) * 2 * 2048 +
                      wave * 64 * 8 + lane * 8;
  const u16* al_src = hk_l + (((size_t)spin * 32 + mtile) * 32) * 2 * 2048 +
                      wave * 64 * 8 + lane * 8;
  const u16* b_src  = (wave < 2 ? w2h : w2l) +
                      ((size_t)spin * NTN + n) * 32 * 2 * 512 + (wave & 1) * 512 +
                      lane * 8;

  f32x16 acc[2][2];
  #pragma unroll
  for (int rt = 0; rt < 2; ++rt)
    #pragma unroll
    for (int ct = 0; ct < 2; ++ct) acc[rt][ct] = (f32x16)(0.f);

  // STAGE(buf, kc): 4 A-gloads + 1 B-gload per wave, all linear 1KB/wave
  #define STAGE(buf, kc)                                                      \
    do {                                                                      \
      size_t ao = (size_t)(kc) * 2 * 2048;                                    \
      gload16(ah_src + ao,        &sAh[buf][0][wave * 64][0]);                \
      gload16(ah_src + ao + 2048, &sAh[buf][1][wave * 64][0]);                \
      gload16(al_src + ao,        &sAl[buf][0][wave * 64][0]);                \
      gload16(al_src + ao + 2048, &sAl[buf][1][wave * 64][0]);                \
      gload16(b_src + (size_t)(kc) * 1024,                                    \
              wave < 2 ? &sBh[buf][wave & 1][0][0] : &sBl[buf][wave & 1][0][0]); \
    } while (0)

  #define COMPUTE(buf)                                                        \
    do {                                                                      \
      half8 ah[2], al[2], bh[2], bl[2];                                       \
      _Pragma("unroll")                                                       \
      for (int rt = 0; rt < 2; ++rt) {                                        \
        ah[rt] = *(const half8*)&sAh[buf][l5][wave * 64 + rt * 32 + l31][0];  \
        al[rt] = *(const half8*)&sAl[buf][l5][wave * 64 + rt * 32 + l31][0];  \
      }                                                                       \
      _Pragma("unroll")                                                       \
      for (int ct = 0; ct < 2; ++ct) {                                        \
        bh[ct] = *(const half8*)&sBh[buf][l5][ct * 32 + l31][0];              \
        bl[ct] = *(const half8*)&sBl[buf][l5][ct * 32 + l31][0];              \
      }                                                                       \
      _Pragma("unroll")                                                       \
      for (int rt = 0; rt < 2; ++rt)                                          \
        _Pragma("unroll")                                                     \
        for (int ct = 0; ct < 2; ++ct) {                                      \
          acc[rt][ct] = __builtin_amdgcn_mfma_f32_32x32x16_f16(al[rt], bh[ct], acc[rt][ct], 0, 0, 0); \
          acc[rt][ct] = __builtin_amdgcn_mfma_f32_32x32x16_f16(ah[rt], bl[ct], acc[rt][ct], 0, 0, 0); \
          acc[rt][ct] = __builtin_amdgcn_mfma_f32_32x32x16_f16(ah[rt], bh[ct], acc[rt][ct], 0, 0, 0); \
        }                                                                     \
    } while (0)

  STAGE(0, 0);
  __syncthreads();
  int cur = 0;
  for (int kc = 0; kc < 31; ++kc) {
    STAGE(cur ^ 1, kc + 1);
    COMPUTE(cur);
    __syncthreads();
    cur ^= 1;
  }
  COMPUTE(cur);

  const float invs = 1.0f / (SCALE_H * SCALE_W);
  #pragma unroll
  for (int ct = 0; ct < 2; ++ct) {
    int nc = n0 + ct * 32 + l31;
    if (nc < W2N) {
      int s = nc / 50;
      int j = nc - s * 50;
      int si = s - s0;
      float bias = b2[nc];
      #pragma unroll
      for (int rt = 0; rt < 2; ++rt) {
        #pragma unroll
        for (int reg = 0; reg < 16; ++reg) {
          int rr = wave * 64 + rt * 32 + (reg & 3) + 8 * (reg >> 2) + 4 * l5;
          int p = sRank[rr][si];
          if (p >= 0)
            mats[(size_t)(m0 + rr) * MMAT + p * MROW + j] = acc[rt][ct][reg] * invs + bias;
        }
      }
    }
  }
  #undef STAGE
  #undef COMPUTE
}

// ---- K3: 50x50 LU det, wave/matrix, readlane pivot broadcast (no DS) ----
__global__ void __launch_bounds__(256, 8)
k_det(const float* __restrict__ mats, float* __restrict__ detw,
      float* __restrict__ out, int spin) {
  int t = threadIdx.x;
  int wave = t >> 6, lane = t & 63;
  int mb = blockIdx.x * 4 + wave;

  float4 row[13];
  if (lane < NF) {
    const float4* rp = (const float4*)(mats + (size_t)mb * MMAT + lane * MROW);
    #pragma unroll
    for (int q = 0; q < 13; ++q) row[q] = rp[q];
    row[12].z = 0.f;      // pad cols 50,51 (garbage in memory)
    row[12].w = 0.f;
  } else {
    #pragma unroll
    for (int q = 0; q < 13; ++q) row[q] = make_float4(0.f, 0.f, 0.f, 0.f);
  }

  double detd = 1.0;
  int parity = 0;
  int virt = lane;
  bool active = (lane < NF);
  #pragma unroll
  for (int p = 0; p < NF; ++p) {
    const int q_ = p >> 2, e_ = p & 3;
    float4 rq = row[q_];
    float cp = (e_ == 0) ? rq.x : (e_ == 1) ? rq.y : (e_ == 2) ? rq.z : rq.w;
    // packed (|value|, lane) argmax over wave (6 DS ops — the only DS left)
    unsigned bits = __float_as_uint(fabsf(cp)) & 0xFFFFFFC0u;
    unsigned key = active ? (bits | (unsigned)lane) : 0u;
    #pragma unroll
    for (int mm = 32; mm >= 1; mm >>= 1) {
      unsigned o = (unsigned)__shfl_xor((int)key, mm);
      key = key > o ? key : o;
    }
    unsigned ukey = (unsigned)__builtin_amdgcn_readfirstlane((int)key); // SGPR
    int pr = (int)(ukey & 63u);                                         // SGPR
    float v = rlane(cp, pr);                    // v_readlane, wave-uniform
    if (ukey < 64u) v = 0.f;                    // singular: remaining pivots ~0
    detd *= (double)v;
    // permutation parity via virtual swap (readlane: p is compile-time const)
    int vp = __builtin_amdgcn_readlane(virt, p);
    unsigned long long bal = __ballot(virt == pr);
    int l = __ffsll((long long)bal) - 1;
    parity ^= (l != p) ? 1 : 0;
    virt = (lane == p) ? pr : ((lane == l) ? vp : virt);
    // eliminate: pivot-row broadcast via readlane (VALU->SGPR), zero DS
    float invv = (v != 0.f) ? (1.0f / v) : 0.f;
    float mlt = (active && lane != pr) ? (cp * invv) : 0.f;
    active = active && (lane != pr);
    #pragma unroll
    for (int q = (p + 1) >> 2; q < 13; ++q) {
      float px = rlane(row[q].x, pr);
      float py = rlane(row[q].y, pr);
      float pz = rlane(row[q].z, pr);
      float pw = rlane(row[q].w, pr);
      row[q].x = fmaf(-mlt, px, row[q].x);
      row[q].y = fmaf(-mlt, py, row[q].y);
      row[q].z = fmaf(-mlt, pz, row[q].z);
      row[q].w = fmaf(-mlt, pw, row[q].w);
    }
  }
  float det = (float)detd;
  if (parity) det = -det;
  if (lane == 0) {
    if (spin == 0) detw[mb] = det;
    else           out[mb]  = detw[mb] * det;
  }
}

extern "C" void kernel_launch(void* const* d_in, const int* in_sizes, int n_in,
                              void* d_out, int out_size, void* d_ws, size_t ws_size,
                              hipStream_t stream) {
  const float* cfg = (const float*)d_in[0];
  const float* W1u = (const float*)d_in[1];
  const float* b1u = (const float*)d_in[2];
  const float* W2u = (const float*)d_in[3];
  const float* b2u = (const float*)d_in[4];
  const float* W1d = (const float*)d_in[5];
  const float* b1d = (const float*)d_in[6];
  const float* W2d = (const float*)d_in[7];
  const float* b2d = (const float*)d_in[8];

  char* ws = (char*)d_ws;
  float* mats = (float*)ws;                 ws += (size_t)B_ * MMAT * 4;       // 85.2 MB
  u16*   hk_h = (u16*)ws;                   ws += (size_t)2 * B_ * H_ * 2;     // 16.8 MB
  u16*   hk_l = (u16*)ws;                   ws += (size_t)2 * B_ * H_ * 2;     // 16.8 MB
  u16*   w2h  = (u16*)ws;                   ws += (size_t)2 * NTN * 32 * 2 * 512 * 2; // 10.35 MB
  u16*   w2l  = (u16*)ws;                   ws += (size_t)2 * NTN * 32 * 2 * 512 * 2; // 10.35 MB
  signed char* rank8 = (signed char*)ws;    ws += (size_t)2 * B_ * S_;         // 1.64 MB
  float* detw = (float*)ws;
  float* out  = (float*)d_out;

  k_prep  <<<dim3(NTN, 8, 2), 256, 0, stream>>>(W2u, W2d, w2h, w2l);
  k_hidden<<<dim3(B_, 2), 256, 0, stream>>>(cfg, W1u, b1u, W1d, b1d, hk_h, hk_l, rank8);
  for (int spin = 0; spin < 2; ++spin) {
    const float* b2 = spin ? b2d : b2u;
    k_gemm<<<dim3(32, NTN), 256, 0, stream>>>(hk_h, hk_l, w2h, w2l, b2, rank8, mats, spin);
    k_det <<<B_ / 4, 256, 0, stream>>>(mats, detw, out, spin);
  }
}